// Round 14
// baseline (256.928 us; speedup 1.0000x reference)
//
#include <hip/hip_runtime.h>
#include <math.h>

#define NB 8192
#define NIN 64
#define NOUT 128
#define NHID 32
#define NEXO 3
#define EXROWS 192
#define NTGT 2

typedef float f32x2 __attribute__((ext_vector_type(2)));
typedef float f32x4 __attribute__((ext_vector_type(4)));
typedef short bf16x8 __attribute__((ext_vector_type(8)));

__device__ __forceinline__ float sigmoidf(float x) {
    return 1.0f / (1.0f + __expf(-x));
}

__device__ __forceinline__ unsigned short f2bf(float x) {   // RNE float->bf16
    unsigned int u = __float_as_uint(x);
    unsigned int r = u + 0x7fffu + ((u >> 16) & 1u);
    return (unsigned short)(r >> 16);
}
__device__ __forceinline__ float bf2f(unsigned short h) {
    return __uint_as_float((unsigned int)h << 16);
}

// packed fp32 FMA, src0 word-broadcast from a pair (par selects lo/hi word).
__device__ __forceinline__ void pk_fma_bc(f32x2& acc, f32x2 wpair, int par, f32x2 y2) {
    if (par == 0)
        asm("v_pk_fma_f32 %0, %1, %2, %0 op_sel:[0,0,0] op_sel_hi:[0,1,1]"
            : "+v"(acc) : "v"(wpair), "v"(y2));
    else
        asm("v_pk_fma_f32 %0, %1, %2, %0 op_sel:[1,0,0] op_sel_hi:[1,1,1]"
            : "+v"(acc) : "v"(wpair), "v"(y2));
}

// DPP-based cross-lane add (VALU pipe).
template<int CTRL>
__device__ __forceinline__ float dpp_add(float x) {
    int p = __builtin_amdgcn_update_dpp(0, __float_as_int(x), CTRL, 0xf, 0xf, true);
    return x + __int_as_float(p);
}
__device__ __forceinline__ float swz_add_xor16(float x) {   // ds_swizzle xor16
    int p = __builtin_amdgcn_ds_swizzle(__float_as_int(x), 0x401f);
    return x + __int_as_float(p);
}

// -------------------------------------------------------------------------
// Kernel A (MFMA): E[b,i,o] = b1+b3 + out1_exog + out2_exog, written to out.
// (unchanged from rounds 5-13)
// -------------------------------------------------------------------------
__global__ __launch_bounds__(256, 4) void narx_exog_kernel(
    const float* __restrict__ exog,
    const float* __restrict__ W1, const float* __restrict__ b1,
    const float* __restrict__ W2, const float* __restrict__ b2,
    const float* __restrict__ W3, const float* __restrict__ b3,
    float* __restrict__ E)
{
    __shared__ __align__(16) float exs[NEXO][EXROWS];
    __shared__ __align__(16) unsigned short exrep[NEXO * 8][200];
    __shared__ __align__(16) unsigned short w2bf[NEXO * 32][72];
    __shared__ __align__(16) float2 w1e2[NEXO][NIN];
    __shared__ __align__(16) float b2l[96];
    __shared__ __align__(16) float w3l[2][96];

    const int tid = threadIdx.x;
    const int b = blockIdx.x;
    const float* exb = exog + (size_t)b * (EXROWS * NEXO);

    for (int idx = tid; idx < EXROWS * NEXO; idx += 256) {
        int t = idx / 3;
        int e = idx - t * 3;
        exs[e][t] = exb[idx];
    }
    for (int idx = tid; idx < 6144; idx += 256) {
        int e = idx >> 11;
        int rem = idx & 2047;
        int u = rem >> 6, t = rem & 63;
        w2bf[e * 32 + u][t] = f2bf(W2[(size_t)(64 + e * 32 + u) * NIN + t]);
    }
    for (int idx = tid; idx < 192; idx += 256) {
        int e = idx >> 6, t = idx & 63;
        w1e2[e][t] = make_float2(W1[t * 5 + 2 + e], W1[320 + t * 5 + 2 + e]);
    }
    if (tid < 96)  b2l[tid] = b2[64 + tid];
    for (int idx = tid; idx < 192; idx += 256) {
        int o = idx / 96, u = idx - o * 96;
        w3l[o][u] = W3[o * 160 + 64 + u];
    }
    __syncthreads();

    for (int idx = tid; idx < NEXO * 8 * 192; idx += 256) {
        int e = idx / 1536;
        int rem = idx - e * 1536;
        int r = rem / 192;
        int q = rem - r * 192;
        float v = (q + r < 192) ? exs[e][q + r] : 0.f;
        exrep[e * 8 + r][q] = f2bf(v);
    }
    __syncthreads();

    const int wv = tid >> 6;
    const int l  = tid & 63;
    const int iw = wv * 32;
    const int lg = l >> 4;
    const int col = l & 15;

    float acc0[2] = {0.f, 0.f};
    float acc1[2] = {0.f, 0.f};

    #pragma unroll 1
    for (int e = 0; e < NEXO; ++e) {
        f32x4 b2v[2], w30v[2], w31v[2];
        #pragma unroll
        for (int mt = 0; mt < 2; ++mt) {
            b2v[mt]  = *(const f32x4*)&b2l[e * 32 + mt * 16 + lg * 4];
            w30v[mt] = *(const f32x4*)&w3l[0][e * 32 + mt * 16 + lg * 4];
            w31v[mt] = *(const f32x4*)&w3l[1][e * 32 + mt * 16 + lg * 4];
        }

        f32x4 cacc[2][2];
        #pragma unroll
        for (int mt = 0; mt < 2; ++mt)
            #pragma unroll
            for (int nt = 0; nt < 2; ++nt)
                cacc[mt][nt] = b2v[mt];

        #pragma unroll
        for (int kt = 0; kt < 2; ++kt) {
            bf16x8 af[2], bfr[2];
            #pragma unroll
            for (int mt = 0; mt < 2; ++mt)
                af[mt] = *(const bf16x8*)&w2bf[e * 32 + mt * 16 + col][kt * 32 + lg * 8];
            #pragma unroll
            for (int nt = 0; nt < 2; ++nt)
                bfr[nt] = *(const bf16x8*)&exrep[e * 8 + (l & 7)]
                              [iw + nt * 16 + kt * 32 + lg * 8 + ((l >> 3) & 1) * 8];
            #pragma unroll
            for (int mt = 0; mt < 2; ++mt)
                #pragma unroll
                for (int nt = 0; nt < 2; ++nt)
                    cacc[mt][nt] = __builtin_amdgcn_mfma_f32_16x16x32_bf16(
                        af[mt], bfr[nt], cacc[mt][nt], 0, 0, 0);
        }

        #pragma unroll
        for (int mt = 0; mt < 2; ++mt)
            #pragma unroll
            for (int nt = 0; nt < 2; ++nt) {
                #pragma unroll
                for (int r = 0; r < 4; ++r) {
                    float sg = sigmoidf(cacc[mt][nt][r]);
                    acc0[nt] += w30v[mt][r] * sg;
                    acc1[nt] += w31v[mt][r] * sg;
                }
            }

        const float* exs_e = &exs[e][0];
        #pragma unroll
        for (int dt = 0; dt < 16; ++dt) {
            float2 wv2 = w1e2[e][lg * 16 + dt];
            float x0 = exs_e[iw + l + dt];
            float x1 = exs_e[iw + 16 + l + dt];
            acc0[0] += wv2.x * x0;
            acc1[0] += wv2.y * x0;
            acc0[1] += wv2.x * x1;
            acc1[1] += wv2.y * x1;
        }
    }

    #pragma unroll
    for (int nt = 0; nt < 2; ++nt) {
        acc0[nt] += __shfl_xor(acc0[nt], 16, 64);
        acc0[nt] += __shfl_xor(acc0[nt], 32, 64);
        acc1[nt] += __shfl_xor(acc1[nt], 16, 64);
        acc1[nt] += __shfl_xor(acc1[nt], 32, 64);
    }
    if (lg == 0) {
        const float bias0 = b1[0] + b3[0];
        const float bias1 = b1[1] + b3[1];
        #pragma unroll
        for (int nt = 0; nt < 2; ++nt) {
            int i = iw + nt * 16 + col;
            *(float2*)&E[(size_t)b * (NOUT * NTGT) + i * 2] =
                make_float2(acc0[nt] + bias0, acc1[nt] + bias1);
        }
    }
}

// -------------------------------------------------------------------------
// Kernel B v14: MFMA static dot. 256 threads = 4 independent waves, each one
// batch-pair. Per chunk: P_static[64 units][16 = 2 batches x 8 lags] via
// 24 mfma_f32_16x16x32_bf16 (4 M-tiles x 2 K-steps x 3 hi/lo passes), C
// transposed through a wave-private LDS buffer back to lane-per-unit. bf16
// windows keep future rows ZERO (invariant) so MFMA = exact known-row sum;
// in-chunk tails + out1 path stay fp32 (r13's proven step core). No
// barriers in the main loop (all LDS traffic wave-private).
// -------------------------------------------------------------------------
#define CH 8
#define NCH 16

__global__ __launch_bounds__(256) void narx_recur_kernel(
    const float* __restrict__ target,
    const float* __restrict__ W1,
    const float* __restrict__ W2, const float* __restrict__ b2,
    const float* __restrict__ W3,
    float* __restrict__ out)
{
    __shared__ __align__(16) f32x2 yw[4][NTGT][192];            // fp32 window (batch-packed)
    __shared__ __align__(16) unsigned short ybf[4][2][NTGT][2][200]; // [w][hl][s][batch][row]
    __shared__ __align__(16) f32x2 ew[4][NTGT][NOUT];           // E
    __shared__ __align__(16) float pt[4][16][68];               // C transpose buffer

    const int tid = threadIdx.x;
    const int w   = tid >> 6;
    const int l   = tid & 63;
    const int s   = l >> 5;
    const int h   = l & 31;
    const size_t bA = ((size_t)blockIdx.x * 4 + w) * 2;
    const size_t bB = bA + 1;

    // ---- zero this wave's bf16 windows (3200 B = 800 dwords, 13/lane) ----
    {
        unsigned int* z = (unsigned int*)&ybf[w][0][0][0][0];
        for (int idx = l; idx < 800; idx += 64) z[idx] = 0u;
    }
    {   // E -> LDS (lane covers rows 2l, 2l+1)
        float4 eA = *(const float4*)&out[bA * (NOUT * NTGT) + l * 4];
        float4 eB = *(const float4*)&out[bB * (NOUT * NTGT) + l * 4];
        ew[w][0][2 * l]     = f32x2{eA.x, eB.x};
        ew[w][1][2 * l]     = f32x2{eA.y, eB.y};
        ew[w][0][2 * l + 1] = f32x2{eA.z, eB.z};
        ew[w][1][2 * l + 1] = f32x2{eA.w, eB.w};
    }
    {   // initial window rows (lane covers row l), fp32 + bf16 hi/lo
        float2 tA = *(const float2*)&target[bA * (NIN * NTGT) + l * 2];
        float2 tB = *(const float2*)&target[bB * (NIN * NTGT) + l * 2];
        yw[w][0][l] = f32x2{tA.x, tB.x};
        yw[w][1][l] = f32x2{tA.y, tB.y};
        float v[2][2] = {{tA.x, tB.x}, {tA.y, tB.y}};
        #pragma unroll
        for (int ss = 0; ss < 2; ++ss)
            #pragma unroll
            for (int q = 0; q < 2; ++q) {
                unsigned short hi = f2bf(v[ss][q]);
                ybf[w][0][ss][q][l] = hi;
                ybf[w][1][ss][q][l] = f2bf(v[ss][q] - bf2f(hi));
            }
    }
    __syncthreads();   // paranoia only (all LDS is wave-private)

    // ---- A fragments: W2 target rows as bf16 hi/lo, loaded once ----
    // A[m][k]: m = l&15 (+16*mt), k = 8*(l>>4)+j (+32*kt)
    bf16x8 ahf[4][2], alf[4][2];
    {
        const int m0 = l & 15, k0 = (l >> 4) * 8;
        #pragma unroll
        for (int mt = 0; mt < 4; ++mt)
            #pragma unroll
            for (int kt = 0; kt < 2; ++kt) {
                const float* wp = W2 + (size_t)(mt * 16 + m0) * NIN + kt * 32 + k0;
                #pragma unroll
                for (int j = 0; j < 8; ++j) {
                    float x = wp[j];
                    unsigned short hi = f2bf(x);
                    ahf[mt][kt][j] = (short)hi;
                    alf[mt][kt][j] = (short)f2bf(x - bf2f(hi));
                }
            }
    }

    // ---- per-lane constants for the steps phase ----
    const float bb = b2[l];
    const f32x2 bbp = {bb, bb};
    const f32x2 w3p  = {W3[s * 160 + l], W3[(1 - s) * 160 + l]};
    const f32x2 wo1p = {W1[s * 320 + (2 * h) * 5 + s],
                        W1[s * 320 + (2 * h + 1) * 5 + s]};
    const f32x2 wo2p = {W1[(1 - s) * 320 + (2 * h) * 5 + s],
                        W1[(1 - s) * 320 + (2 * h + 1) * 5 + s]};
    f32x2 w2tp[4];                  // own-unit taps 57..63 packed as pairs
    {
        const float* wp = W2 + (size_t)l * NIN + 57;
        w2tp[0] = f32x2{wp[0], wp[1]};
        w2tp[1] = f32x2{wp[2], wp[3]};
        w2tp[2] = f32x2{wp[4], wp[5]};
        w2tp[3] = f32x2{wp[6], wp[6]};
    }

    f32x2* Y = &yw[w][s][0];
    const f32x2* EV = &ew[w][s][0];

    // B-frag addressing: col n = l&15 -> lag = n&7, batch q = n>>3; k0 = 8*(l>>4)
    const int lag = l & 7;
    const int qb  = (l >> 3) & 1;
    const int bk0 = (l >> 4) * 8;
    const unsigned short* pH0 = &ybf[w][0][0][qb][0];
    const unsigned short* pL0 = &ybf[w][1][0][qb][0];
    const unsigned short* pH1 = &ybf[w][0][1][qb][0];
    const unsigned short* pL1 = &ybf[w][1][1][qb][0];

    #pragma unroll 1
    for (int c = 0; c < NCH; ++c) {
        const int i0 = c * CH;

        // ---- MFMA static dot: P[u][n] over known rows (future rows are 0) ----
        f32x4 acc[4];
        #pragma unroll
        for (int mt = 0; mt < 4; ++mt) acc[mt] = f32x4{0.f, 0.f, 0.f, 0.f};

        #pragma unroll
        for (int kt = 0; kt < 2; ++kt) {
            const int base = i0 + lag + kt * 32 + bk0;
            bf16x8 bh0, bl0, bh1, bl1;
            #pragma unroll
            for (int j = 0; j < 8; ++j) {
                bh0[j] = (short)pH0[base + j];
                bl0[j] = (short)pL0[base + j];
                bh1[j] = (short)pH1[base + j];
                bl1[j] = (short)pL1[base + j];
            }
            #pragma unroll
            for (int mt = 0; mt < 4; ++mt) {
                const bf16x8 bh = (mt < 2) ? bh0 : bh1;
                const bf16x8 bl = (mt < 2) ? bl0 : bl1;
                acc[mt] = __builtin_amdgcn_mfma_f32_16x16x32_bf16(ahf[mt][kt], bh, acc[mt], 0, 0, 0);
                acc[mt] = __builtin_amdgcn_mfma_f32_16x16x32_bf16(ahf[mt][kt], bl, acc[mt], 0, 0, 0);
                acc[mt] = __builtin_amdgcn_mfma_f32_16x16x32_bf16(alf[mt][kt], bh, acc[mt], 0, 0, 0);
            }
        }

        // ---- transpose C -> lane-per-unit via wave-private LDS ----
        {
            const int n = l & 15;
            const int r0 = (l >> 4) * 4;
            #pragma unroll
            for (int mt = 0; mt < 4; ++mt)
                *(f32x4*)&pt[w][n][mt * 16 + r0] = acc[mt];
        }
        f32x2 P2[CH];
        #pragma unroll
        for (int ci = 0; ci < CH; ++ci)
            P2[ci] = f32x2{pt[w][ci][l], pt[w][ci + 8][l]} + bbp;

        // ---- 8 sequential steps (r13 proven core) ----
        f32x2 predprev = Y[i0 + 63];

        #pragma unroll
        for (int ci = 0; ci < CH; ++ci) {
            const int i = i0 + ci;
            const f32x2 y1a = Y[i + 2 * h];
            const f32x2 y1b = Y[i + 2 * h + 1];
            const f32x2 ev  = EV[i];

            f32x2 sg;
            sg.x = sigmoidf(P2[ci].x);
            sg.y = sigmoidf(P2[ci].y);

            f32x2 va = {0.f, 0.f}, vb = {0.f, 0.f};
            pk_fma_bc(va, w3p, 0, sg);
            pk_fma_bc(vb, w3p, 1, sg);
            pk_fma_bc(va, wo1p, 0, y1a);
            pk_fma_bc(va, wo1p, 1, y1b);
            pk_fma_bc(vb, wo2p, 0, y1a);
            pk_fma_bc(vb, wo2p, 1, y1b);

            auto r0 = __builtin_amdgcn_permlane32_swap(
                __float_as_uint(vb.x), __float_as_uint(vb.x), false, false);
            auto r1 = __builtin_amdgcn_permlane32_swap(
                __float_as_uint(vb.y), __float_as_uint(vb.y), false, false);
            f32x2 cc2;
            cc2.x = va.x + (s ? __uint_as_float(r0[0]) : __uint_as_float(r0[1]));
            cc2.y = va.y + (s ? __uint_as_float(r1[0]) : __uint_as_float(r1[1]));
            cc2.x = swz_add_xor16(cc2.x);  cc2.y = swz_add_xor16(cc2.y);
            cc2.x = dpp_add<0x128>(cc2.x); cc2.y = dpp_add<0x128>(cc2.y);
            cc2.x = dpp_add<0x141>(cc2.x); cc2.y = dpp_add<0x141>(cc2.y);
            cc2.x = dpp_add<0x4E>(cc2.x);  cc2.y = dpp_add<0x4E>(cc2.y);
            cc2.x = dpp_add<0xB1>(cc2.x);  cc2.y = dpp_add<0xB1>(cc2.y);

            const f32x2 pred = cc2 + ev + predprev;

            // in-chunk recurrent tails, fp32 exact
            #pragma unroll
            for (int cj = ci + 1; cj < CH; ++cj) {
                const int d = cj - ci;            // 1..7
                const int j = 7 - d;              // tap 64-d
                pk_fma_bc(P2[cj], w2tp[j >> 1], j & 1, pred);
            }
            if (h == 0) Y[i + NIN] = pred;        // fp32 window (next steps/chunks)
            if (h == 1) {                         // bf16 hi/lo windows (next chunk's MFMA)
                unsigned short hA = f2bf(pred.x);
                unsigned short hB = f2bf(pred.y);
                ybf[w][0][s][0][i + NIN] = hA;
                ybf[w][0][s][1][i + NIN] = hB;
                ybf[w][1][s][0][i + NIN] = f2bf(pred.x - bf2f(hA));
                ybf[w][1][s][1][i + NIN] = f2bf(pred.y - bf2f(hB));
            }
            predprev = pred;
        }
    }

    // ---- dump: lane l covers output rows 2l, 2l+1 for both batches ----
    {
        f32x2 a0 = yw[w][0][NIN + 2 * l];
        f32x2 a1 = yw[w][1][NIN + 2 * l];
        f32x2 c0 = yw[w][0][NIN + 2 * l + 1];
        f32x2 c1 = yw[w][1][NIN + 2 * l + 1];
        *(float4*)&out[bA * (NOUT * NTGT) + l * 4] = make_float4(a0.x, a1.x, c0.x, c1.x);
        *(float4*)&out[bB * (NOUT * NTGT) + l * 4] = make_float4(a0.y, a1.y, c0.y, c1.y);
    }
}

extern "C" void kernel_launch(void* const* d_in, const int* in_sizes, int n_in,
                              void* d_out, int out_size, void* d_ws, size_t ws_size,
                              hipStream_t stream) {
    (void)in_sizes; (void)n_in; (void)out_size; (void)d_ws; (void)ws_size;
    const float* target = (const float*)d_in[0];
    const float* exog   = (const float*)d_in[1];
    const float* W1     = (const float*)d_in[2];
    const float* b1     = (const float*)d_in[3];
    const float* W2     = (const float*)d_in[4];
    const float* b2     = (const float*)d_in[5];
    const float* W3     = (const float*)d_in[6];
    const float* b3     = (const float*)d_in[7];
    float* out = (float*)d_out;

    hipLaunchKernelGGL(narx_exog_kernel, dim3(NB), dim3(256), 0, stream,
                       exog, W1, b1, W2, b2, W3, b3, out);
    hipLaunchKernelGGL(narx_recur_kernel, dim3(NB / 8), dim3(256), 0, stream,
                       target, W1, W2, b2, W3, out);
}

// Round 15
// 222.619 us; speedup vs baseline: 1.1541x; 1.1541x over previous
//
#include <hip/hip_runtime.h>
#include <math.h>

#define NB 8192
#define NIN 64
#define NOUT 128
#define NHID 32
#define NEXO 3
#define EXROWS 192
#define NTGT 2

typedef float f32x2 __attribute__((ext_vector_type(2)));
typedef float f32x4 __attribute__((ext_vector_type(4)));
typedef int   i32x4 __attribute__((ext_vector_type(4)));
typedef short bf16x8 __attribute__((ext_vector_type(8)));

__device__ __forceinline__ float sigmoidf(float x) {
    return 1.0f / (1.0f + __expf(-x));
}

__device__ __forceinline__ unsigned short f2bf(float x) {   // RNE float->bf16
    unsigned int u = __float_as_uint(x);
    unsigned int r = u + 0x7fffu + ((u >> 16) & 1u);
    return (unsigned short)(r >> 16);
}
__device__ __forceinline__ float bf2f(unsigned short h) {
    return __uint_as_float((unsigned int)h << 16);
}

// DPP-based cross-lane add (VALU pipe). Masks {1,2,7,8} span the 16-group.
template<int CTRL>
__device__ __forceinline__ float dpp_add(float x) {
    int p = __builtin_amdgcn_update_dpp(0, __float_as_int(x), CTRL, 0xf, 0xf, true);
    return x + __int_as_float(p);
}

// exchange with lane^16 (series partner). Primary: permlane16_swap (VALU);
// fallback: ds_swizzle xor16 (proven r6+).
#if __has_builtin(__builtin_amdgcn_permlane16_swap)
__device__ __forceinline__ f32x2 xchg16(f32x2 v, int s) {
    auto rx = __builtin_amdgcn_permlane16_swap(__float_as_uint(v.x), __float_as_uint(v.x), false, false);
    auto ry = __builtin_amdgcn_permlane16_swap(__float_as_uint(v.y), __float_as_uint(v.y), false, false);
    f32x2 r;
    r.x = s ? __uint_as_float(rx[0]) : __uint_as_float(rx[1]);
    r.y = s ? __uint_as_float(ry[0]) : __uint_as_float(ry[1]);
    return r;
}
#else
__device__ __forceinline__ f32x2 xchg16(f32x2 v, int s) {
    (void)s;
    f32x2 r;
    r.x = __int_as_float(__builtin_amdgcn_ds_swizzle(__float_as_int(v.x), 0x401f));
    r.y = __int_as_float(__builtin_amdgcn_ds_swizzle(__float_as_int(v.y), 0x401f));
    return r;
}
#endif

// fold across lane^32 (unit bit 4): proven permlane32_swap pattern (r7+).
__device__ __forceinline__ f32x2 fold32(f32x2 v, int s32) {
    auto rx = __builtin_amdgcn_permlane32_swap(__float_as_uint(v.x), __float_as_uint(v.x), false, false);
    auto ry = __builtin_amdgcn_permlane32_swap(__float_as_uint(v.y), __float_as_uint(v.y), false, false);
    f32x2 o;
    o.x = v.x + (s32 ? __uint_as_float(rx[0]) : __uint_as_float(rx[1]));
    o.y = v.y + (s32 ? __uint_as_float(ry[0]) : __uint_as_float(ry[1]));
    return o;
}

// -------------------------------------------------------------------------
// Kernel A (MFMA): E[b,i,o] = b1+b3 + out1_exog + out2_exog, written to out.
// (unchanged from rounds 5-14)
// -------------------------------------------------------------------------
__global__ __launch_bounds__(256, 4) void narx_exog_kernel(
    const float* __restrict__ exog,
    const float* __restrict__ W1, const float* __restrict__ b1,
    const float* __restrict__ W2, const float* __restrict__ b2,
    const float* __restrict__ W3, const float* __restrict__ b3,
    float* __restrict__ E)
{
    __shared__ __align__(16) float exs[NEXO][EXROWS];
    __shared__ __align__(16) unsigned short exrep[NEXO * 8][200];
    __shared__ __align__(16) unsigned short w2bf[NEXO * 32][72];
    __shared__ __align__(16) float2 w1e2[NEXO][NIN];
    __shared__ __align__(16) float b2l[96];
    __shared__ __align__(16) float w3l[2][96];

    const int tid = threadIdx.x;
    const int b = blockIdx.x;
    const float* exb = exog + (size_t)b * (EXROWS * NEXO);

    for (int idx = tid; idx < EXROWS * NEXO; idx += 256) {
        int t = idx / 3;
        int e = idx - t * 3;
        exs[e][t] = exb[idx];
    }
    for (int idx = tid; idx < 6144; idx += 256) {
        int e = idx >> 11;
        int rem = idx & 2047;
        int u = rem >> 6, t = rem & 63;
        w2bf[e * 32 + u][t] = f2bf(W2[(size_t)(64 + e * 32 + u) * NIN + t]);
    }
    for (int idx = tid; idx < 192; idx += 256) {
        int e = idx >> 6, t = idx & 63;
        w1e2[e][t] = make_float2(W1[t * 5 + 2 + e], W1[320 + t * 5 + 2 + e]);
    }
    if (tid < 96)  b2l[tid] = b2[64 + tid];
    for (int idx = tid; idx < 192; idx += 256) {
        int o = idx / 96, u = idx - o * 96;
        w3l[o][u] = W3[o * 160 + 64 + u];
    }
    __syncthreads();

    for (int idx = tid; idx < NEXO * 8 * 192; idx += 256) {
        int e = idx / 1536;
        int rem = idx - e * 1536;
        int r = rem / 192;
        int q = rem - r * 192;
        float v = (q + r < 192) ? exs[e][q + r] : 0.f;
        exrep[e * 8 + r][q] = f2bf(v);
    }
    __syncthreads();

    const int wv = tid >> 6;
    const int l  = tid & 63;
    const int iw = wv * 32;
    const int lg = l >> 4;
    const int col = l & 15;

    float acc0[2] = {0.f, 0.f};
    float acc1[2] = {0.f, 0.f};

    #pragma unroll 1
    for (int e = 0; e < NEXO; ++e) {
        f32x4 b2v[2], w30v[2], w31v[2];
        #pragma unroll
        for (int mt = 0; mt < 2; ++mt) {
            b2v[mt]  = *(const f32x4*)&b2l[e * 32 + mt * 16 + lg * 4];
            w30v[mt] = *(const f32x4*)&w3l[0][e * 32 + mt * 16 + lg * 4];
            w31v[mt] = *(const f32x4*)&w3l[1][e * 32 + mt * 16 + lg * 4];
        }

        f32x4 cacc[2][2];
        #pragma unroll
        for (int mt = 0; mt < 2; ++mt)
            #pragma unroll
            for (int nt = 0; nt < 2; ++nt)
                cacc[mt][nt] = b2v[mt];

        #pragma unroll
        for (int kt = 0; kt < 2; ++kt) {
            bf16x8 af[2], bfr[2];
            #pragma unroll
            for (int mt = 0; mt < 2; ++mt)
                af[mt] = *(const bf16x8*)&w2bf[e * 32 + mt * 16 + col][kt * 32 + lg * 8];
            #pragma unroll
            for (int nt = 0; nt < 2; ++nt)
                bfr[nt] = *(const bf16x8*)&exrep[e * 8 + (l & 7)]
                              [iw + nt * 16 + kt * 32 + lg * 8 + ((l >> 3) & 1) * 8];
            #pragma unroll
            for (int mt = 0; mt < 2; ++mt)
                #pragma unroll
                for (int nt = 0; nt < 2; ++nt)
                    cacc[mt][nt] = __builtin_amdgcn_mfma_f32_16x16x32_bf16(
                        af[mt], bfr[nt], cacc[mt][nt], 0, 0, 0);
        }

        #pragma unroll
        for (int mt = 0; mt < 2; ++mt)
            #pragma unroll
            for (int nt = 0; nt < 2; ++nt) {
                #pragma unroll
                for (int r = 0; r < 4; ++r) {
                    float sg = sigmoidf(cacc[mt][nt][r]);
                    acc0[nt] += w30v[mt][r] * sg;
                    acc1[nt] += w31v[mt][r] * sg;
                }
            }

        const float* exs_e = &exs[e][0];
        #pragma unroll
        for (int dt = 0; dt < 16; ++dt) {
            float2 wv2 = w1e2[e][lg * 16 + dt];
            float x0 = exs_e[iw + l + dt];
            float x1 = exs_e[iw + 16 + l + dt];
            acc0[0] += wv2.x * x0;
            acc1[0] += wv2.y * x0;
            acc0[1] += wv2.x * x1;
            acc1[1] += wv2.y * x1;
        }
    }

    #pragma unroll
    for (int nt = 0; nt < 2; ++nt) {
        acc0[nt] += __shfl_xor(acc0[nt], 16, 64);
        acc0[nt] += __shfl_xor(acc0[nt], 32, 64);
        acc1[nt] += __shfl_xor(acc1[nt], 16, 64);
        acc1[nt] += __shfl_xor(acc1[nt], 32, 64);
    }
    if (lg == 0) {
        const float bias0 = b1[0] + b3[0];
        const float bias1 = b1[1] + b3[1];
        #pragma unroll
        for (int nt = 0; nt < 2; ++nt) {
            int i = iw + nt * 16 + col;
            *(float2*)&E[(size_t)b * (NOUT * NTGT) + i * 2] =
                make_float2(acc0[nt] + bias0, acc1[nt] + bias1);
        }
    }
}

// -------------------------------------------------------------------------
// Kernel B v15: one 64-thread wave per block, one batch-pair. MFMA static
// dot with packed-u32 hi/lo windows (aligned b32 reads + v_perm), pt[u][20]
// transpose (b128 row reads), per-chunk ev prefetch, all-VALU reduce
// (xchg16 + DPP{1,2,7,8} + fold32). Unit map: s=(l>>4)&1, h=(l&15)|((l>>5)<<4).
// No barriers (same-wave DS ordering, proven r10/r13/r14).
// -------------------------------------------------------------------------
#define CH 8
#define NCH 16

__global__ __launch_bounds__(64) void narx_recur_kernel(
    const float* __restrict__ target,
    const float* __restrict__ W1,
    const float* __restrict__ W2, const float* __restrict__ b2,
    const float* __restrict__ W3,
    float* __restrict__ out)
{
    __shared__ __align__(16) f32x2 yw[NTGT][EXROWS];         // fp32 window, 3 KB
    __shared__ __align__(16) unsigned int ypk[NTGT][2][200]; // {hi | lo<<16} per (s,q), 3.2 KB
    __shared__ __align__(16) f32x2 ew[NTGT][NOUT];           // E, 2 KB
    __shared__ __align__(16) float pt[64][20];               // transpose buf, 5 KB

    const int l = threadIdx.x;
    const int s   = (l >> 4) & 1;                 // series group
    const int h   = (l & 15) | ((l >> 5) << 4);   // hidden unit within series
    const int u   = s * NHID + h;                 // global unit = W2 row
    const int s32 = (l >> 5) & 1;
    const size_t bA = (size_t)blockIdx.x * 2;
    const size_t bB = bA + 1;

    // ---- zero packed windows ----
    for (int i = l; i < NTGT * 2 * 200; i += 64) ((unsigned int*)ypk)[i] = 0u;

    {   // E -> LDS (lane covers rows 2l, 2l+1)
        float4 eA = *(const float4*)&out[bA * (NOUT * NTGT) + l * 4];
        float4 eB = *(const float4*)&out[bB * (NOUT * NTGT) + l * 4];
        ew[0][2 * l]     = f32x2{eA.x, eB.x};
        ew[1][2 * l]     = f32x2{eA.y, eB.y};
        ew[0][2 * l + 1] = f32x2{eA.z, eB.z};
        ew[1][2 * l + 1] = f32x2{eA.w, eB.w};
    }
    {   // initial window rows (lane covers row l): fp32 + packed bf16 hi/lo
        float2 tA = *(const float2*)&target[bA * (NIN * NTGT) + l * 2];
        float2 tB = *(const float2*)&target[bB * (NIN * NTGT) + l * 2];
        yw[0][l] = f32x2{tA.x, tB.x};
        yw[1][l] = f32x2{tA.y, tB.y};
        float v[2][2] = {{tA.x, tB.x}, {tA.y, tB.y}};
        #pragma unroll
        for (int ss = 0; ss < 2; ++ss)
            #pragma unroll
            for (int q = 0; q < 2; ++q) {
                unsigned short hi = f2bf(v[ss][q]);
                unsigned short lo = f2bf(v[ss][q] - bf2f(hi));
                ypk[ss][q][l] = (unsigned int)hi | ((unsigned int)lo << 16);
            }
    }

    // ---- A fragments: W2 rows as bf16 hi/lo (raw-lane MFMA mapping) ----
    bf16x8 ahf[4][2], alf[4][2];
    {
        const int m0 = l & 15, k0 = (l >> 4) * 8;
        #pragma unroll
        for (int mt = 0; mt < 4; ++mt)
            #pragma unroll
            for (int kt = 0; kt < 2; ++kt) {
                const float* wp = W2 + (size_t)(mt * 16 + m0) * NIN + kt * 32 + k0;
                #pragma unroll
                for (int j = 0; j < 8; ++j) {
                    float x = wp[j];
                    unsigned short hi = f2bf(x);
                    ahf[mt][kt][j] = (short)hi;
                    alf[mt][kt][j] = (short)f2bf(x - bf2f(hi));
                }
            }
    }

    // ---- per-lane constants ----
    const float bb    = b2[u];
    const float w3own = W3[s * 160 + u];
    const float w3oth = W3[(1 - s) * 160 + u];
    const float wo1a  = W1[s * 320 + (2 * h) * 5 + s];
    const float wo1b  = W1[s * 320 + (2 * h + 1) * 5 + s];
    const float wo2a  = W1[(1 - s) * 320 + (2 * h) * 5 + s];
    const float wo2b  = W1[(1 - s) * 320 + (2 * h + 1) * 5 + s];
    float w2t[7];
    #pragma unroll
    for (int j = 0; j < 7; ++j) w2t[j] = W2[(size_t)u * NIN + 57 + j];

    f32x2* Y = &yw[s][0];
    const f32x2* EV = &ew[s][0];

    // B-frag addressing: col n = l&15 -> lag = n&7, batch q = n>>3
    const int lag = l & 7;
    const int qb  = (l >> 3) & 1;
    const int bk0 = (l >> 4) * 8;
    const unsigned int* pk0 = &ypk[0][qb][0];
    const unsigned int* pk1 = &ypk[1][qb][0];

    #pragma unroll 1
    for (int c = 0; c < NCH; ++c) {
        const int i0 = c * CH;

        // ---- MFMA static dot over known rows (future rows are zero) ----
        f32x4 acc[4];
        #pragma unroll
        for (int mt = 0; mt < 4; ++mt) acc[mt] = f32x4{0.f, 0.f, 0.f, 0.f};

        #pragma unroll
        for (int kt = 0; kt < 2; ++kt) {
            const int base = i0 + lag + bk0 + kt * 32;
            unsigned int r0[8], r1[8];
            #pragma unroll
            for (int j = 0; j < 8; ++j) { r0[j] = pk0[base + j]; r1[j] = pk1[base + j]; }
            i32x4 h0, l0, h1, l1;
            #pragma unroll
            for (int j2 = 0; j2 < 4; ++j2) {
                h0[j2] = (int)__builtin_amdgcn_perm(r0[2*j2+1], r0[2*j2], 0x05040100u);
                l0[j2] = (int)__builtin_amdgcn_perm(r0[2*j2+1], r0[2*j2], 0x07060302u);
                h1[j2] = (int)__builtin_amdgcn_perm(r1[2*j2+1], r1[2*j2], 0x05040100u);
                l1[j2] = (int)__builtin_amdgcn_perm(r1[2*j2+1], r1[2*j2], 0x07060302u);
            }
            const bf16x8 bh0 = __builtin_bit_cast(bf16x8, h0);
            const bf16x8 bl0 = __builtin_bit_cast(bf16x8, l0);
            const bf16x8 bh1 = __builtin_bit_cast(bf16x8, h1);
            const bf16x8 bl1 = __builtin_bit_cast(bf16x8, l1);
            #pragma unroll
            for (int mt = 0; mt < 4; ++mt) {
                const bf16x8 bh = (mt < 2) ? bh0 : bh1;
                const bf16x8 bl = (mt < 2) ? bl0 : bl1;
                acc[mt] = __builtin_amdgcn_mfma_f32_16x16x32_bf16(ahf[mt][kt], bh, acc[mt], 0, 0, 0);
                acc[mt] = __builtin_amdgcn_mfma_f32_16x16x32_bf16(ahf[mt][kt], bl, acc[mt], 0, 0, 0);
                acc[mt] = __builtin_amdgcn_mfma_f32_16x16x32_bf16(alf[mt][kt], bh, acc[mt], 0, 0, 0);
            }
        }

        // ---- transpose C via pt[u][n] (16 b32 writes, 2-way = free) ----
        {
            const int n = l & 15, r0w = (l >> 4) * 4;
            #pragma unroll
            for (int mt = 0; mt < 4; ++mt)
                #pragma unroll
                for (int r = 0; r < 4; ++r)
                    pt[mt * 16 + r0w + r][n] = acc[mt][r];
        }
        // own row: 4 b128 reads -> P2
        f32x4 pa = *(const f32x4*)&pt[u][0];
        f32x4 pb = *(const f32x4*)&pt[u][4];
        f32x4 pc = *(const f32x4*)&pt[u][8];
        f32x4 pd = *(const f32x4*)&pt[u][12];
        f32x2 P2[CH];
        #pragma unroll
        for (int ci = 0; ci < 4; ++ci) {
            P2[ci]     = f32x2{pa[ci], pc[ci]} + bb;
            P2[ci + 4] = f32x2{pb[ci], pd[ci]} + bb;
        }

        // ---- prefetch E for the chunk (4 b128) + predprev ----
        f32x2 ev8[CH];
        #pragma unroll
        for (int q = 0; q < 4; ++q) {
            f32x4 e4 = *(const f32x4*)&EV[i0 + 2 * q];
            ev8[2 * q]     = f32x2{e4[0], e4[1]};
            ev8[2 * q + 1] = f32x2{e4[2], e4[3]};
        }
        f32x2 predprev = Y[i0 + 63];

        // ---- 8 sequential steps ----
        #pragma unroll
        for (int ci = 0; ci < CH; ++ci) {
            const int i = i0 + ci;
            const f32x2 y1a = Y[i + 2 * h];
            const f32x2 y1b = Y[i + 2 * h + 1];

            f32x2 sg;
            sg.x = sigmoidf(P2[ci].x);
            sg.y = sigmoidf(P2[ci].y);

            f32x2 va = w3own * sg + wo1a * y1a + wo1b * y1b;   // own-series output
            f32x2 vb = w3oth * sg + wo2a * y1a + wo2b * y1b;   // other output

            // cc = va + partner's vb (lane^16 = same h, other series)
            f32x2 cc = va + xchg16(vb, s);
            // reduce over unit bits {0,1,2,3} (DPP) then bit4 (lane^32 fold)
            cc.x = dpp_add<0xB1>(cc.x);  cc.y = dpp_add<0xB1>(cc.y);   // xor1
            cc.x = dpp_add<0x4E>(cc.x);  cc.y = dpp_add<0x4E>(cc.y);   // xor2
            cc.x = dpp_add<0x141>(cc.x); cc.y = dpp_add<0x141>(cc.y);  // xor7
            cc.x = dpp_add<0x128>(cc.x); cc.y = dpp_add<0x128>(cc.y);  // xor8
            cc = fold32(cc, s32);

            const f32x2 pred = cc + ev8[ci] + predprev;

            // in-chunk recurrent tails (fp32 exact)
            #pragma unroll
            for (int cj = ci + 1; cj < CH; ++cj)
                P2[cj] += w2t[7 - (cj - ci)] * pred;

            if ((l & 47) == 0) Y[i + NIN] = pred;   // l = 0 (s=0), 16 (s=1)
            if ((l & 47) == 1) {                    // packed windows for next chunks
                unsigned short hA = f2bf(pred.x);
                unsigned short hB = f2bf(pred.y);
                unsigned short lA = f2bf(pred.x - bf2f(hA));
                unsigned short lB = f2bf(pred.y - bf2f(hB));
                ypk[s][0][i + NIN] = (unsigned int)hA | ((unsigned int)lA << 16);
                ypk[s][1][i + NIN] = (unsigned int)hB | ((unsigned int)lB << 16);
            }
            predprev = pred;
        }
    }

    // ---- dump: lane l covers output rows 2l, 2l+1 for both batches ----
    {
        f32x2 a0 = yw[0][NIN + 2 * l];
        f32x2 a1 = yw[1][NIN + 2 * l];
        f32x2 c0 = yw[0][NIN + 2 * l + 1];
        f32x2 c1 = yw[1][NIN + 2 * l + 1];
        *(float4*)&out[bA * (NOUT * NTGT) + l * 4] = make_float4(a0.x, a1.x, c0.x, c1.x);
        *(float4*)&out[bB * (NOUT * NTGT) + l * 4] = make_float4(a0.y, a1.y, c0.y, c1.y);
    }
}

extern "C" void kernel_launch(void* const* d_in, const int* in_sizes, int n_in,
                              void* d_out, int out_size, void* d_ws, size_t ws_size,
                              hipStream_t stream) {
    (void)in_sizes; (void)n_in; (void)out_size; (void)d_ws; (void)ws_size;
    const float* target = (const float*)d_in[0];
    const float* exog   = (const float*)d_in[1];
    const float* W1     = (const float*)d_in[2];
    const float* b1     = (const float*)d_in[3];
    const float* W2     = (const float*)d_in[4];
    const float* b2     = (const float*)d_in[5];
    const float* W3     = (const float*)d_in[6];
    const float* b3     = (const float*)d_in[7];
    float* out = (float*)d_out;

    hipLaunchKernelGGL(narx_exog_kernel, dim3(NB), dim3(256), 0, stream,
                       exog, W1, b1, W2, b2, W3, b3, out);
    hipLaunchKernelGGL(narx_recur_kernel, dim3(NB / 2), dim3(64), 0, stream,
                       target, W1, W2, b2, W3, out);
}

// Round 16
// 211.210 us; speedup vs baseline: 1.2165x; 1.0540x over previous
//
#include <hip/hip_runtime.h>
#include <math.h>

#define NB 8192
#define NIN 64
#define NOUT 128
#define NHID 32
#define NEXO 3
#define EXROWS 192
#define NTGT 2

typedef float f32x2 __attribute__((ext_vector_type(2)));
typedef float f32x4 __attribute__((ext_vector_type(4)));
typedef int   i32x4 __attribute__((ext_vector_type(4)));
typedef short bf16x8 __attribute__((ext_vector_type(8)));

// ws layout (bytes): [0) W2A bf16[6144] | [12288) W2BH bf16[4096] |
// [20480) W2BL bf16[4096] | [28672) WP float[672] (w1e2 384 | w3l 192 | b2l 96)
#define WS_W2A  0
#define WS_W2BH 12288
#define WS_W2BL 20480
#define WS_WP   28672

__device__ __forceinline__ float sigmoidf(float x) {
    return 1.0f / (1.0f + __expf(-x));
}

__device__ __forceinline__ unsigned short f2bf(float x) {   // RNE float->bf16
    unsigned int u = __float_as_uint(x);
    unsigned int r = u + 0x7fffu + ((u >> 16) & 1u);
    return (unsigned short)(r >> 16);
}
__device__ __forceinline__ float bf2f(unsigned short h) {
    return __uint_as_float((unsigned int)h << 16);
}

template<int CTRL>
__device__ __forceinline__ float dpp_add(float x) {
    int p = __builtin_amdgcn_update_dpp(0, __float_as_int(x), CTRL, 0xf, 0xf, true);
    return x + __int_as_float(p);
}

#if __has_builtin(__builtin_amdgcn_permlane16_swap)
__device__ __forceinline__ f32x2 xchg16(f32x2 v, int s) {
    auto rx = __builtin_amdgcn_permlane16_swap(__float_as_uint(v.x), __float_as_uint(v.x), false, false);
    auto ry = __builtin_amdgcn_permlane16_swap(__float_as_uint(v.y), __float_as_uint(v.y), false, false);
    f32x2 r;
    r.x = s ? __uint_as_float(rx[0]) : __uint_as_float(rx[1]);
    r.y = s ? __uint_as_float(ry[0]) : __uint_as_float(ry[1]);
    return r;
}
#else
__device__ __forceinline__ f32x2 xchg16(f32x2 v, int s) {
    (void)s;
    f32x2 r;
    r.x = __int_as_float(__builtin_amdgcn_ds_swizzle(__float_as_int(v.x), 0x401f));
    r.y = __int_as_float(__builtin_amdgcn_ds_swizzle(__float_as_int(v.y), 0x401f));
    return r;
}
#endif

__device__ __forceinline__ f32x2 fold32(f32x2 v, int s32) {
    auto rx = __builtin_amdgcn_permlane32_swap(__float_as_uint(v.x), __float_as_uint(v.x), false, false);
    auto ry = __builtin_amdgcn_permlane32_swap(__float_as_uint(v.y), __float_as_uint(v.y), false, false);
    f32x2 o;
    o.x = v.x + (s32 ? __uint_as_float(rx[0]) : __uint_as_float(rx[1]));
    o.y = v.y + (s32 ? __uint_as_float(ry[0]) : __uint_as_float(ry[1]));
    return o;
}

// -------------------------------------------------------------------------
// Kernel A0: one-block weight prepack into ws (runs every launch; tiny).
// -------------------------------------------------------------------------
__global__ __launch_bounds__(256) void narx_prepack_kernel(
    const float* __restrict__ W1, const float* __restrict__ W2,
    const float* __restrict__ W3, const float* __restrict__ b2,
    unsigned char* __restrict__ ws)
{
    const int tid = threadIdx.x;
    unsigned short* w2a  = (unsigned short*)(ws + WS_W2A);
    unsigned short* w2bh = (unsigned short*)(ws + WS_W2BH);
    unsigned short* w2bl = (unsigned short*)(ws + WS_W2BL);
    float* wp = (float*)(ws + WS_WP);

    // W2A[e][mt][kt][col][lg][j] for kernel A fragments
    for (int idx = tid; idx < 6144; idx += 256) {
        int rem = idx;
        int j = rem & 7;  rem >>= 3;
        int lg = rem & 3; rem >>= 2;
        int col = rem & 15; rem >>= 4;
        int kt = rem & 1; rem >>= 1;
        int mt = rem & 1; rem >>= 1;
        int e = rem;
        int row = 64 + e * 32 + mt * 16 + col;
        int t = kt * 32 + lg * 8 + j;
        w2a[idx] = f2bf(W2[(size_t)row * NIN + t]);
    }
    // W2BH/W2BL[mt][kt][m0][k0g][j] hi/lo planes for kernel B A-fragments
    for (int idx = tid; idx < 4096; idx += 256) {
        int rem = idx;
        int j = rem & 7;   rem >>= 3;
        int k0g = rem & 3; rem >>= 2;
        int m0 = rem & 15; rem >>= 4;
        int kt = rem & 1;  rem >>= 1;
        int mt = rem;
        int row = mt * 16 + m0;
        int t = kt * 32 + k0g * 8 + j;
        float x = W2[(size_t)row * NIN + t];
        unsigned short hi = f2bf(x);
        w2bh[idx] = hi;
        w2bl[idx] = f2bf(x - bf2f(hi));
    }
    // WP: w1e2 [e][t]{o0,o1} (384), w3l [o][u] (192), b2l (96)
    for (int idx = tid; idx < 384; idx += 256) {
        int e = idx >> 7;
        int r = idx & 127;
        int t = r >> 1, o = r & 1;
        wp[idx] = W1[o * 320 + t * 5 + 2 + e];
    }
    if (tid < 192) wp[384 + tid] = W3[(tid / 96) * 160 + 64 + (tid % 96)];
    if (tid < 96)  wp[576 + tid] = b2[64 + tid];
}

// -------------------------------------------------------------------------
// Kernel A v2 (MFMA): E[b,i,o] = b1+b3 + out1_exog + out2_exog -> out.
// Weights from ws prepack: af fragments load direct from global blob
// (no w2bf LDS), small tables staged by linear copy. LDS ~14.6 KB.
// -------------------------------------------------------------------------
__global__ __launch_bounds__(256, 4) void narx_exog_kernel(
    const float* __restrict__ exog,
    const float* __restrict__ b1, const float* __restrict__ b3,
    const unsigned char* __restrict__ ws,
    float* __restrict__ E)
{
    __shared__ __align__(16) float exs[NEXO][EXROWS];
    __shared__ __align__(16) unsigned short exrep[NEXO * 8][200];
    __shared__ __align__(16) float2 w1e2[NEXO][NIN];
    __shared__ __align__(16) float w3l[2][96];
    __shared__ __align__(16) float b2l[96];

    const unsigned short* w2a = (const unsigned short*)(ws + WS_W2A);
    const float* wp = (const float*)(ws + WS_WP);

    const int tid = threadIdx.x;
    const int b = blockIdx.x;
    const float* exb = exog + (size_t)b * (EXROWS * NEXO);

    for (int idx = tid; idx < EXROWS * NEXO; idx += 256) {
        int t = idx / 3;
        int e = idx - t * 3;
        exs[e][t] = exb[idx];
    }
    // small tables: linear copies from the prepack blob
    for (int idx = tid; idx < 384; idx += 256) ((float*)w1e2)[idx] = wp[idx];
    if (tid < 192) ((float*)w3l)[tid] = wp[384 + tid];
    if (tid < 96)  b2l[tid] = wp[576 + tid];
    __syncthreads();

    for (int idx = tid; idx < NEXO * 8 * 192; idx += 256) {
        int e = idx / 1536;
        int rem = idx - e * 1536;
        int r = rem / 192;
        int q = rem - r * 192;
        float v = (q + r < 192) ? exs[e][q + r] : 0.f;
        exrep[e * 8 + r][q] = f2bf(v);
    }
    __syncthreads();

    const int wv = tid >> 6;
    const int l  = tid & 63;
    const int iw = wv * 32;
    const int lg = l >> 4;
    const int col = l & 15;

    float acc0[2] = {0.f, 0.f};
    float acc1[2] = {0.f, 0.f};

    #pragma unroll 1
    for (int e = 0; e < NEXO; ++e) {
        f32x4 b2v[2], w30v[2], w31v[2];
        #pragma unroll
        for (int mt = 0; mt < 2; ++mt) {
            b2v[mt]  = *(const f32x4*)&b2l[e * 32 + mt * 16 + lg * 4];
            w30v[mt] = *(const f32x4*)&w3l[0][e * 32 + mt * 16 + lg * 4];
            w31v[mt] = *(const f32x4*)&w3l[1][e * 32 + mt * 16 + lg * 4];
        }

        f32x4 cacc[2][2];
        #pragma unroll
        for (int mt = 0; mt < 2; ++mt)
            #pragma unroll
            for (int nt = 0; nt < 2; ++nt)
                cacc[mt][nt] = b2v[mt];

        #pragma unroll
        for (int kt = 0; kt < 2; ++kt) {
            bf16x8 af[2], bfr[2];
            #pragma unroll
            for (int mt = 0; mt < 2; ++mt)
                af[mt] = *(const bf16x8*)(w2a + ((size_t)((e * 2 + mt) * 2 + kt)) * 512
                                              + col * 32 + lg * 8);
            #pragma unroll
            for (int nt = 0; nt < 2; ++nt)
                bfr[nt] = *(const bf16x8*)&exrep[e * 8 + (l & 7)]
                              [iw + nt * 16 + kt * 32 + lg * 8 + ((l >> 3) & 1) * 8];
            #pragma unroll
            for (int mt = 0; mt < 2; ++mt)
                #pragma unroll
                for (int nt = 0; nt < 2; ++nt)
                    cacc[mt][nt] = __builtin_amdgcn_mfma_f32_16x16x32_bf16(
                        af[mt], bfr[nt], cacc[mt][nt], 0, 0, 0);
        }

        #pragma unroll
        for (int mt = 0; mt < 2; ++mt)
            #pragma unroll
            for (int nt = 0; nt < 2; ++nt) {
                #pragma unroll
                for (int r = 0; r < 4; ++r) {
                    float sg = sigmoidf(cacc[mt][nt][r]);
                    acc0[nt] += w30v[mt][r] * sg;
                    acc1[nt] += w31v[mt][r] * sg;
                }
            }

        const float* exs_e = &exs[e][0];
        #pragma unroll
        for (int dt = 0; dt < 16; ++dt) {
            float2 wv2 = w1e2[e][lg * 16 + dt];
            float x0 = exs_e[iw + l + dt];
            float x1 = exs_e[iw + 16 + l + dt];
            acc0[0] += wv2.x * x0;
            acc1[0] += wv2.y * x0;
            acc0[1] += wv2.x * x1;
            acc1[1] += wv2.y * x1;
        }
    }

    #pragma unroll
    for (int nt = 0; nt < 2; ++nt) {
        acc0[nt] += __shfl_xor(acc0[nt], 16, 64);
        acc0[nt] += __shfl_xor(acc0[nt], 32, 64);
        acc1[nt] += __shfl_xor(acc1[nt], 16, 64);
        acc1[nt] += __shfl_xor(acc1[nt], 32, 64);
    }
    if (lg == 0) {
        const float bias0 = b1[0] + b3[0];
        const float bias1 = b1[1] + b3[1];
        #pragma unroll
        for (int nt = 0; nt < 2; ++nt) {
            int i = iw + nt * 16 + col;
            *(float2*)&E[(size_t)b * (NOUT * NTGT) + i * 2] =
                make_float2(acc0[nt] + bias0, acc1[nt] + bias1);
        }
    }
}

// -------------------------------------------------------------------------
// Kernel B v16: r15 + prepacked A-fragments (16 b128 loads) + chunk-start
// batched bf16 packing (replaces per-step masked pack). One 64-thread wave
// per block, one batch-pair, no barriers in the main loop.
// -------------------------------------------------------------------------
#define CH 8
#define NCH 16

__global__ __launch_bounds__(64) void narx_recur_kernel(
    const float* __restrict__ target,
    const float* __restrict__ W1,
    const float* __restrict__ W2, const float* __restrict__ b2,
    const float* __restrict__ W3,
    const unsigned char* __restrict__ ws,
    float* __restrict__ out)
{
    __shared__ __align__(16) f32x2 yw[NTGT][EXROWS];
    __shared__ __align__(16) unsigned int ypk[NTGT][2][200];
    __shared__ __align__(16) f32x2 ew[NTGT][NOUT];
    __shared__ __align__(16) float pt[64][20];

    const unsigned short* w2bh = (const unsigned short*)(ws + WS_W2BH);
    const unsigned short* w2bl = (const unsigned short*)(ws + WS_W2BL);

    const int l = threadIdx.x;
    const int s   = (l >> 4) & 1;
    const int h   = (l & 15) | ((l >> 5) << 4);
    const int u   = s * NHID + h;
    const int s32 = (l >> 5) & 1;
    const size_t bA = (size_t)blockIdx.x * 2;
    const size_t bB = bA + 1;

    for (int i = l; i < NTGT * 2 * 200; i += 64) ((unsigned int*)ypk)[i] = 0u;

    {   // E -> LDS
        float4 eA = *(const float4*)&out[bA * (NOUT * NTGT) + l * 4];
        float4 eB = *(const float4*)&out[bB * (NOUT * NTGT) + l * 4];
        ew[0][2 * l]     = f32x2{eA.x, eB.x};
        ew[1][2 * l]     = f32x2{eA.y, eB.y};
        ew[0][2 * l + 1] = f32x2{eA.z, eB.z};
        ew[1][2 * l + 1] = f32x2{eA.w, eB.w};
    }
    {   // initial window rows: fp32 + packed bf16 hi/lo
        float2 tA = *(const float2*)&target[bA * (NIN * NTGT) + l * 2];
        float2 tB = *(const float2*)&target[bB * (NIN * NTGT) + l * 2];
        yw[0][l] = f32x2{tA.x, tB.x};
        yw[1][l] = f32x2{tA.y, tB.y};
        float v[2][2] = {{tA.x, tB.x}, {tA.y, tB.y}};
        #pragma unroll
        for (int ss = 0; ss < 2; ++ss)
            #pragma unroll
            for (int q = 0; q < 2; ++q) {
                unsigned short hi = f2bf(v[ss][q]);
                unsigned short lo = f2bf(v[ss][q] - bf2f(hi));
                ypk[ss][q][l] = (unsigned int)hi | ((unsigned int)lo << 16);
            }
    }

    // ---- A fragments from prepacked hi/lo planes: 16 b128 loads ----
    bf16x8 ahf[4][2], alf[4][2];
    {
        const int m0 = l & 15, k0g = l >> 4;
        #pragma unroll
        for (int mt = 0; mt < 4; ++mt)
            #pragma unroll
            for (int kt = 0; kt < 2; ++kt) {
                const int off = ((mt * 2 + kt) * 16 + m0) * 32 + k0g * 8;
                ahf[mt][kt] = *(const bf16x8*)(w2bh + off);
                alf[mt][kt] = *(const bf16x8*)(w2bl + off);
            }
    }

    // ---- per-lane constants ----
    const float bb    = b2[u];
    const float w3own = W3[s * 160 + u];
    const float w3oth = W3[(1 - s) * 160 + u];
    const float wo1a  = W1[s * 320 + (2 * h) * 5 + s];
    const float wo1b  = W1[s * 320 + (2 * h + 1) * 5 + s];
    const float wo2a  = W1[(1 - s) * 320 + (2 * h) * 5 + s];
    const float wo2b  = W1[(1 - s) * 320 + (2 * h + 1) * 5 + s];
    float w2t[7];
    #pragma unroll
    for (int j = 0; j < 7; ++j) w2t[j] = W2[(size_t)u * NIN + 57 + j];

    f32x2* Y = &yw[s][0];
    const f32x2* EV = &ew[s][0];

    const int lag = l & 7;
    const int qb  = (l >> 3) & 1;
    const int bk0 = (l >> 4) * 8;
    const unsigned int* pk0 = &ypk[0][qb][0];
    const unsigned int* pk1 = &ypk[1][qb][0];

    #pragma unroll 1
    for (int c = 0; c < NCH; ++c) {
        const int i0 = c * CH;

        // ---- chunk-start batch pack of last chunk's 8 new rows ----
        if (c > 0 && l < 16) {
            const int ss = l >> 3, j = l & 7;
            const int row = i0 + 56 + j;
            f32x2 v = yw[ss][row];
            unsigned short hA = f2bf(v.x);
            unsigned short hB = f2bf(v.y);
            ypk[ss][0][row] = (unsigned int)hA | ((unsigned int)f2bf(v.x - bf2f(hA)) << 16);
            ypk[ss][1][row] = (unsigned int)hB | ((unsigned int)f2bf(v.y - bf2f(hB)) << 16);
        }

        // ---- MFMA static dot over known rows (future rows are zero) ----
        f32x4 acc[4];
        #pragma unroll
        for (int mt = 0; mt < 4; ++mt) acc[mt] = f32x4{0.f, 0.f, 0.f, 0.f};

        #pragma unroll
        for (int kt = 0; kt < 2; ++kt) {
            const int base = i0 + lag + bk0 + kt * 32;
            unsigned int r0[8], r1[8];
            #pragma unroll
            for (int j = 0; j < 8; ++j) { r0[j] = pk0[base + j]; r1[j] = pk1[base + j]; }
            i32x4 h0, l0, h1, l1;
            #pragma unroll
            for (int j2 = 0; j2 < 4; ++j2) {
                h0[j2] = (int)__builtin_amdgcn_perm(r0[2*j2+1], r0[2*j2], 0x05040100u);
                l0[j2] = (int)__builtin_amdgcn_perm(r0[2*j2+1], r0[2*j2], 0x07060302u);
                h1[j2] = (int)__builtin_amdgcn_perm(r1[2*j2+1], r1[2*j2], 0x05040100u);
                l1[j2] = (int)__builtin_amdgcn_perm(r1[2*j2+1], r1[2*j2], 0x07060302u);
            }
            const bf16x8 bh0 = __builtin_bit_cast(bf16x8, h0);
            const bf16x8 bl0 = __builtin_bit_cast(bf16x8, l0);
            const bf16x8 bh1 = __builtin_bit_cast(bf16x8, h1);
            const bf16x8 bl1 = __builtin_bit_cast(bf16x8, l1);
            #pragma unroll
            for (int mt = 0; mt < 4; ++mt) {
                const bf16x8 bh = (mt < 2) ? bh0 : bh1;
                const bf16x8 bl = (mt < 2) ? bl0 : bl1;
                acc[mt] = __builtin_amdgcn_mfma_f32_16x16x32_bf16(ahf[mt][kt], bh, acc[mt], 0, 0, 0);
                acc[mt] = __builtin_amdgcn_mfma_f32_16x16x32_bf16(ahf[mt][kt], bl, acc[mt], 0, 0, 0);
                acc[mt] = __builtin_amdgcn_mfma_f32_16x16x32_bf16(alf[mt][kt], bh, acc[mt], 0, 0, 0);
            }
        }

        // ---- transpose C via pt[u][n] ----
        {
            const int n = l & 15, r0w = (l >> 4) * 4;
            #pragma unroll
            for (int mt = 0; mt < 4; ++mt)
                #pragma unroll
                for (int r = 0; r < 4; ++r)
                    pt[mt * 16 + r0w + r][n] = acc[mt][r];
        }
        f32x4 pa = *(const f32x4*)&pt[u][0];
        f32x4 pb = *(const f32x4*)&pt[u][4];
        f32x4 pc = *(const f32x4*)&pt[u][8];
        f32x4 pd = *(const f32x4*)&pt[u][12];
        f32x2 P2[CH];
        #pragma unroll
        for (int ci = 0; ci < 4; ++ci) {
            P2[ci]     = f32x2{pa[ci], pc[ci]} + bb;
            P2[ci + 4] = f32x2{pb[ci], pd[ci]} + bb;
        }

        // ---- prefetch E for the chunk ----
        f32x2 ev8[CH];
        #pragma unroll
        for (int q = 0; q < 4; ++q) {
            f32x4 e4 = *(const f32x4*)&EV[i0 + 2 * q];
            ev8[2 * q]     = f32x2{e4[0], e4[1]};
            ev8[2 * q + 1] = f32x2{e4[2], e4[3]};
        }
        f32x2 predprev = Y[i0 + 63];

        // ---- 8 sequential steps ----
        #pragma unroll
        for (int ci = 0; ci < CH; ++ci) {
            const int i = i0 + ci;
            const f32x2 y1a = Y[i + 2 * h];
            const f32x2 y1b = Y[i + 2 * h + 1];

            f32x2 sg;
            sg.x = sigmoidf(P2[ci].x);
            sg.y = sigmoidf(P2[ci].y);

            f32x2 va = w3own * sg + wo1a * y1a + wo1b * y1b;
            f32x2 vb = w3oth * sg + wo2a * y1a + wo2b * y1b;

            f32x2 cc = va + xchg16(vb, s);
            cc.x = dpp_add<0xB1>(cc.x);  cc.y = dpp_add<0xB1>(cc.y);
            cc.x = dpp_add<0x4E>(cc.x);  cc.y = dpp_add<0x4E>(cc.y);
            cc.x = dpp_add<0x141>(cc.x); cc.y = dpp_add<0x141>(cc.y);
            cc.x = dpp_add<0x128>(cc.x); cc.y = dpp_add<0x128>(cc.y);
            cc = fold32(cc, s32);

            const f32x2 pred = cc + ev8[ci] + predprev;

            #pragma unroll
            for (int cj = ci + 1; cj < CH; ++cj)
                P2[cj] += w2t[7 - (cj - ci)] * pred;

            if ((l & 47) == 0) Y[i + NIN] = pred;   // fp32 window only
            predprev = pred;
        }
    }

    // ---- dump ----
    {
        f32x2 a0 = yw[0][NIN + 2 * l];
        f32x2 a1 = yw[1][NIN + 2 * l];
        f32x2 c0 = yw[0][NIN + 2 * l + 1];
        f32x2 c1 = yw[1][NIN + 2 * l + 1];
        *(float4*)&out[bA * (NOUT * NTGT) + l * 4] = make_float4(a0.x, a1.x, c0.x, c1.x);
        *(float4*)&out[bB * (NOUT * NTGT) + l * 4] = make_float4(a0.y, a1.y, c0.y, c1.y);
    }
}

extern "C" void kernel_launch(void* const* d_in, const int* in_sizes, int n_in,
                              void* d_out, int out_size, void* d_ws, size_t ws_size,
                              hipStream_t stream) {
    (void)in_sizes; (void)n_in; (void)out_size; (void)ws_size;
    const float* target = (const float*)d_in[0];
    const float* exog   = (const float*)d_in[1];
    const float* W1     = (const float*)d_in[2];
    const float* b1     = (const float*)d_in[3];
    const float* W2     = (const float*)d_in[4];
    const float* b2     = (const float*)d_in[5];
    const float* W3     = (const float*)d_in[6];
    const float* b3     = (const float*)d_in[7];
    float* out = (float*)d_out;
    unsigned char* ws = (unsigned char*)d_ws;

    hipLaunchKernelGGL(narx_prepack_kernel, dim3(1), dim3(256), 0, stream,
                       W1, W2, W3, b2, ws);
    hipLaunchKernelGGL(narx_exog_kernel, dim3(NB), dim3(256), 0, stream,
                       exog, b1, b3, ws, out);
    hipLaunchKernelGGL(narx_recur_kernel, dim3(NB / 2), dim3(64), 0, stream,
                       target, W1, W2, b2, W3, ws, out);
}

// Round 17
// 203.316 us; speedup vs baseline: 1.2637x; 1.0388x over previous
//
#include <hip/hip_runtime.h>
#include <math.h>

#define NB 8192
#define NIN 64
#define NOUT 128
#define NHID 32
#define NEXO 3
#define EXROWS 192
#define NTGT 2

typedef float f32x2 __attribute__((ext_vector_type(2)));
typedef float f32x4 __attribute__((ext_vector_type(4)));
typedef int   i32x4 __attribute__((ext_vector_type(4)));
typedef short bf16x8 __attribute__((ext_vector_type(8)));

// ws layout (bytes): [0) W2A bf16[6144] | [12288) W2BH bf16[4096] |
// [20480) W2BL bf16[4096] | [28672) WP float[672] (w1e2 384 | w3l 192 | b2l 96)
#define WS_W2A  0
#define WS_W2BH 12288
#define WS_W2BL 20480
#define WS_WP   28672

__device__ __forceinline__ float sigmoidf(float x) {
    return 1.0f / (1.0f + __expf(-x));
}

__device__ __forceinline__ unsigned short f2bf(float x) {   // RNE float->bf16
    unsigned int u = __float_as_uint(x);
    unsigned int r = u + 0x7fffu + ((u >> 16) & 1u);
    return (unsigned short)(r >> 16);
}
__device__ __forceinline__ float bf2f(unsigned short h) {
    return __uint_as_float((unsigned int)h << 16);
}

template<int CTRL>
__device__ __forceinline__ float dpp_add(float x) {
    int p = __builtin_amdgcn_update_dpp(0, __float_as_int(x), CTRL, 0xf, 0xf, true);
    return x + __int_as_float(p);
}

#if __has_builtin(__builtin_amdgcn_permlane16_swap)
__device__ __forceinline__ f32x2 xchg16(f32x2 v, int s) {
    auto rx = __builtin_amdgcn_permlane16_swap(__float_as_uint(v.x), __float_as_uint(v.x), false, false);
    auto ry = __builtin_amdgcn_permlane16_swap(__float_as_uint(v.y), __float_as_uint(v.y), false, false);
    f32x2 r;
    r.x = s ? __uint_as_float(rx[0]) : __uint_as_float(rx[1]);
    r.y = s ? __uint_as_float(ry[0]) : __uint_as_float(ry[1]);
    return r;
}
#else
__device__ __forceinline__ f32x2 xchg16(f32x2 v, int s) {
    (void)s;
    f32x2 r;
    r.x = __int_as_float(__builtin_amdgcn_ds_swizzle(__float_as_int(v.x), 0x401f));
    r.y = __int_as_float(__builtin_amdgcn_ds_swizzle(__float_as_int(v.y), 0x401f));
    return r;
}
#endif

__device__ __forceinline__ f32x2 fold32(f32x2 v, int s32) {
    auto rx = __builtin_amdgcn_permlane32_swap(__float_as_uint(v.x), __float_as_uint(v.x), false, false);
    auto ry = __builtin_amdgcn_permlane32_swap(__float_as_uint(v.y), __float_as_uint(v.y), false, false);
    f32x2 o;
    o.x = v.x + (s32 ? __uint_as_float(rx[0]) : __uint_as_float(rx[1]));
    o.y = v.y + (s32 ? __uint_as_float(ry[0]) : __uint_as_float(ry[1]));
    return o;
}

// -------------------------------------------------------------------------
// Kernel A0: one-block weight prepack into ws (unchanged from round 16).
// -------------------------------------------------------------------------
__global__ __launch_bounds__(256) void narx_prepack_kernel(
    const float* __restrict__ W1, const float* __restrict__ W2,
    const float* __restrict__ W3, const float* __restrict__ b2,
    unsigned char* __restrict__ ws)
{
    const int tid = threadIdx.x;
    unsigned short* w2a  = (unsigned short*)(ws + WS_W2A);
    unsigned short* w2bh = (unsigned short*)(ws + WS_W2BH);
    unsigned short* w2bl = (unsigned short*)(ws + WS_W2BL);
    float* wp = (float*)(ws + WS_WP);

    for (int idx = tid; idx < 6144; idx += 256) {
        int rem = idx;
        int j = rem & 7;  rem >>= 3;
        int lg = rem & 3; rem >>= 2;
        int col = rem & 15; rem >>= 4;
        int kt = rem & 1; rem >>= 1;
        int mt = rem & 1; rem >>= 1;
        int e = rem;
        int row = 64 + e * 32 + mt * 16 + col;
        int t = kt * 32 + lg * 8 + j;
        w2a[idx] = f2bf(W2[(size_t)row * NIN + t]);
    }
    for (int idx = tid; idx < 4096; idx += 256) {
        int rem = idx;
        int j = rem & 7;   rem >>= 3;
        int k0g = rem & 3; rem >>= 2;
        int m0 = rem & 15; rem >>= 4;
        int kt = rem & 1;  rem >>= 1;
        int mt = rem;
        int row = mt * 16 + m0;
        int t = kt * 32 + k0g * 8 + j;
        float x = W2[(size_t)row * NIN + t];
        unsigned short hi = f2bf(x);
        w2bh[idx] = hi;
        w2bl[idx] = f2bf(x - bf2f(hi));
    }
    for (int idx = tid; idx < 384; idx += 256) {
        int e = idx >> 7;
        int r = idx & 127;
        int t = r >> 1, o = r & 1;
        wp[idx] = W1[o * 320 + t * 5 + 2 + e];
    }
    if (tid < 192) wp[384 + tid] = W3[(tid / 96) * 160 + 64 + (tid % 96)];
    if (tid < 96)  wp[576 + tid] = b2[64 + tid];
}

// -------------------------------------------------------------------------
// Kernel A v2 (MFMA): unchanged from round 16.
// -------------------------------------------------------------------------
__global__ __launch_bounds__(256, 4) void narx_exog_kernel(
    const float* __restrict__ exog,
    const float* __restrict__ b1, const float* __restrict__ b3,
    const unsigned char* __restrict__ ws,
    float* __restrict__ E)
{
    __shared__ __align__(16) float exs[NEXO][EXROWS];
    __shared__ __align__(16) unsigned short exrep[NEXO * 8][200];
    __shared__ __align__(16) float2 w1e2[NEXO][NIN];
    __shared__ __align__(16) float w3l[2][96];
    __shared__ __align__(16) float b2l[96];

    const unsigned short* w2a = (const unsigned short*)(ws + WS_W2A);
    const float* wp = (const float*)(ws + WS_WP);

    const int tid = threadIdx.x;
    const int b = blockIdx.x;
    const float* exb = exog + (size_t)b * (EXROWS * NEXO);

    for (int idx = tid; idx < EXROWS * NEXO; idx += 256) {
        int t = idx / 3;
        int e = idx - t * 3;
        exs[e][t] = exb[idx];
    }
    for (int idx = tid; idx < 384; idx += 256) ((float*)w1e2)[idx] = wp[idx];
    if (tid < 192) ((float*)w3l)[tid] = wp[384 + tid];
    if (tid < 96)  b2l[tid] = wp[576 + tid];
    __syncthreads();

    for (int idx = tid; idx < NEXO * 8 * 192; idx += 256) {
        int e = idx / 1536;
        int rem = idx - e * 1536;
        int r = rem / 192;
        int q = rem - r * 192;
        float v = (q + r < 192) ? exs[e][q + r] : 0.f;
        exrep[e * 8 + r][q] = f2bf(v);
    }
    __syncthreads();

    const int wv = tid >> 6;
    const int l  = tid & 63;
    const int iw = wv * 32;
    const int lg = l >> 4;
    const int col = l & 15;

    float acc0[2] = {0.f, 0.f};
    float acc1[2] = {0.f, 0.f};

    #pragma unroll 1
    for (int e = 0; e < NEXO; ++e) {
        f32x4 b2v[2], w30v[2], w31v[2];
        #pragma unroll
        for (int mt = 0; mt < 2; ++mt) {
            b2v[mt]  = *(const f32x4*)&b2l[e * 32 + mt * 16 + lg * 4];
            w30v[mt] = *(const f32x4*)&w3l[0][e * 32 + mt * 16 + lg * 4];
            w31v[mt] = *(const f32x4*)&w3l[1][e * 32 + mt * 16 + lg * 4];
        }

        f32x4 cacc[2][2];
        #pragma unroll
        for (int mt = 0; mt < 2; ++mt)
            #pragma unroll
            for (int nt = 0; nt < 2; ++nt)
                cacc[mt][nt] = b2v[mt];

        #pragma unroll
        for (int kt = 0; kt < 2; ++kt) {
            bf16x8 af[2], bfr[2];
            #pragma unroll
            for (int mt = 0; mt < 2; ++mt)
                af[mt] = *(const bf16x8*)(w2a + ((size_t)((e * 2 + mt) * 2 + kt)) * 512
                                              + col * 32 + lg * 8);
            #pragma unroll
            for (int nt = 0; nt < 2; ++nt)
                bfr[nt] = *(const bf16x8*)&exrep[e * 8 + (l & 7)]
                              [iw + nt * 16 + kt * 32 + lg * 8 + ((l >> 3) & 1) * 8];
            #pragma unroll
            for (int mt = 0; mt < 2; ++mt)
                #pragma unroll
                for (int nt = 0; nt < 2; ++nt)
                    cacc[mt][nt] = __builtin_amdgcn_mfma_f32_16x16x32_bf16(
                        af[mt], bfr[nt], cacc[mt][nt], 0, 0, 0);
        }

        #pragma unroll
        for (int mt = 0; mt < 2; ++mt)
            #pragma unroll
            for (int nt = 0; nt < 2; ++nt) {
                #pragma unroll
                for (int r = 0; r < 4; ++r) {
                    float sg = sigmoidf(cacc[mt][nt][r]);
                    acc0[nt] += w30v[mt][r] * sg;
                    acc1[nt] += w31v[mt][r] * sg;
                }
            }

        const float* exs_e = &exs[e][0];
        #pragma unroll
        for (int dt = 0; dt < 16; ++dt) {
            float2 wv2 = w1e2[e][lg * 16 + dt];
            float x0 = exs_e[iw + l + dt];
            float x1 = exs_e[iw + 16 + l + dt];
            acc0[0] += wv2.x * x0;
            acc1[0] += wv2.y * x0;
            acc0[1] += wv2.x * x1;
            acc1[1] += wv2.y * x1;
        }
    }

    #pragma unroll
    for (int nt = 0; nt < 2; ++nt) {
        acc0[nt] += __shfl_xor(acc0[nt], 16, 64);
        acc0[nt] += __shfl_xor(acc0[nt], 32, 64);
        acc1[nt] += __shfl_xor(acc1[nt], 16, 64);
        acc1[nt] += __shfl_xor(acc1[nt], 32, 64);
    }
    if (lg == 0) {
        const float bias0 = b1[0] + b3[0];
        const float bias1 = b1[1] + b3[1];
        #pragma unroll
        for (int nt = 0; nt < 2; ++nt) {
            int i = iw + nt * 16 + col;
            *(float2*)&E[(size_t)b * (NOUT * NTGT) + i * 2] =
                make_float2(acc0[nt] + bias0, acc1[nt] + bias1);
        }
    }
}

// -------------------------------------------------------------------------
// Kernel B v17: software-pipelined MFMA. At iteration c: pack chunk c-1
// preds -> MFMA+transpose for chunk c+1 issued EARLY (its LDS/MFMA latency
// overlaps the step chain) -> 8 steps of chunk c (also accumulate fp32
// corr[] = chunk-c preds' contributions to chunk c+1, taps 49..63) ->
// P2(next) = pt + bb + corr. Zero-invariant in ypk makes early MFMA exact
// over known rows. One 64-thread wave per block; no barriers in main loop.
// -------------------------------------------------------------------------
#define CH 8
#define NCH 16

__global__ __launch_bounds__(64) void narx_recur_kernel(
    const float* __restrict__ target,
    const float* __restrict__ W1,
    const float* __restrict__ W2, const float* __restrict__ b2,
    const float* __restrict__ W3,
    const unsigned char* __restrict__ ws,
    float* __restrict__ out)
{
    __shared__ __align__(16) f32x2 yw[NTGT][EXROWS];
    __shared__ __align__(16) unsigned int ypk[NTGT][2][200];
    __shared__ __align__(16) f32x2 ew[NTGT][NOUT];
    __shared__ __align__(16) float pt[64][20];

    const unsigned short* w2bh = (const unsigned short*)(ws + WS_W2BH);
    const unsigned short* w2bl = (const unsigned short*)(ws + WS_W2BL);

    const int l = threadIdx.x;
    const int s   = (l >> 4) & 1;
    const int h   = (l & 15) | ((l >> 5) << 4);
    const int u   = s * NHID + h;
    const int s32 = (l >> 5) & 1;
    const size_t bA = (size_t)blockIdx.x * 2;
    const size_t bB = bA + 1;

    for (int i = l; i < NTGT * 2 * 200; i += 64) ((unsigned int*)ypk)[i] = 0u;

    {   // E -> LDS
        float4 eA = *(const float4*)&out[bA * (NOUT * NTGT) + l * 4];
        float4 eB = *(const float4*)&out[bB * (NOUT * NTGT) + l * 4];
        ew[0][2 * l]     = f32x2{eA.x, eB.x};
        ew[1][2 * l]     = f32x2{eA.y, eB.y};
        ew[0][2 * l + 1] = f32x2{eA.z, eB.z};
        ew[1][2 * l + 1] = f32x2{eA.w, eB.w};
    }
    {   // initial window rows: fp32 + packed bf16 hi/lo
        float2 tA = *(const float2*)&target[bA * (NIN * NTGT) + l * 2];
        float2 tB = *(const float2*)&target[bB * (NIN * NTGT) + l * 2];
        yw[0][l] = f32x2{tA.x, tB.x};
        yw[1][l] = f32x2{tA.y, tB.y};
        float v[2][2] = {{tA.x, tB.x}, {tA.y, tB.y}};
        #pragma unroll
        for (int ss = 0; ss < 2; ++ss)
            #pragma unroll
            for (int q = 0; q < 2; ++q) {
                unsigned short hi = f2bf(v[ss][q]);
                unsigned short lo = f2bf(v[ss][q] - bf2f(hi));
                ypk[ss][q][l] = (unsigned int)hi | ((unsigned int)lo << 16);
            }
    }

    // ---- A fragments from prepacked hi/lo planes: 16 b128 loads ----
    bf16x8 ahf[4][2], alf[4][2];
    {
        const int m0 = l & 15, k0g = l >> 4;
        #pragma unroll
        for (int mt = 0; mt < 4; ++mt)
            #pragma unroll
            for (int kt = 0; kt < 2; ++kt) {
                const int off = ((mt * 2 + kt) * 16 + m0) * 32 + k0g * 8;
                ahf[mt][kt] = *(const bf16x8*)(w2bh + off);
                alf[mt][kt] = *(const bf16x8*)(w2bl + off);
            }
    }

    // ---- per-lane constants ----
    const float bb    = b2[u];
    const float w3own = W3[s * 160 + u];
    const float w3oth = W3[(1 - s) * 160 + u];
    const float wo1a  = W1[s * 320 + (2 * h) * 5 + s];
    const float wo1b  = W1[s * 320 + (2 * h + 1) * 5 + s];
    const float wo2a  = W1[(1 - s) * 320 + (2 * h) * 5 + s];
    const float wo2b  = W1[(1 - s) * 320 + (2 * h + 1) * 5 + s];
    float w2x[15];                               // own-unit taps 49..63
    #pragma unroll
    for (int j = 0; j < 15; ++j) w2x[j] = W2[(size_t)u * NIN + 49 + j];

    f32x2* Y = &yw[s][0];
    const f32x2* EV = &ew[s][0];

    const int lag = l & 7;
    const int qb  = (l >> 3) & 1;
    const int bk0 = (l >> 4) * 8;
    const unsigned int* pk0 = &ypk[0][qb][0];
    const unsigned int* pk1 = &ypk[1][qb][0];

    // helper: MFMA static dot for chunk starting at row i0m; result -> pt
    auto mfma_to_pt = [&](const int i0m) {
        f32x4 acc[4];
        #pragma unroll
        for (int mt = 0; mt < 4; ++mt) acc[mt] = f32x4{0.f, 0.f, 0.f, 0.f};
        #pragma unroll
        for (int kt = 0; kt < 2; ++kt) {
            const int base = i0m + lag + bk0 + kt * 32;
            unsigned int r0[8], r1[8];
            #pragma unroll
            for (int j = 0; j < 8; ++j) { r0[j] = pk0[base + j]; r1[j] = pk1[base + j]; }
            i32x4 h0v, l0v, h1v, l1v;
            #pragma unroll
            for (int j2 = 0; j2 < 4; ++j2) {
                h0v[j2] = (int)__builtin_amdgcn_perm(r0[2*j2+1], r0[2*j2], 0x05040100u);
                l0v[j2] = (int)__builtin_amdgcn_perm(r0[2*j2+1], r0[2*j2], 0x07060302u);
                h1v[j2] = (int)__builtin_amdgcn_perm(r1[2*j2+1], r1[2*j2], 0x05040100u);
                l1v[j2] = (int)__builtin_amdgcn_perm(r1[2*j2+1], r1[2*j2], 0x07060302u);
            }
            const bf16x8 bh0 = __builtin_bit_cast(bf16x8, h0v);
            const bf16x8 bl0 = __builtin_bit_cast(bf16x8, l0v);
            const bf16x8 bh1 = __builtin_bit_cast(bf16x8, h1v);
            const bf16x8 bl1 = __builtin_bit_cast(bf16x8, l1v);
            #pragma unroll
            for (int mt = 0; mt < 4; ++mt) {
                const bf16x8 bh = (mt < 2) ? bh0 : bh1;
                const bf16x8 bl = (mt < 2) ? bl0 : bl1;
                acc[mt] = __builtin_amdgcn_mfma_f32_16x16x32_bf16(ahf[mt][kt], bh, acc[mt], 0, 0, 0);
                acc[mt] = __builtin_amdgcn_mfma_f32_16x16x32_bf16(ahf[mt][kt], bl, acc[mt], 0, 0, 0);
                acc[mt] = __builtin_amdgcn_mfma_f32_16x16x32_bf16(alf[mt][kt], bh, acc[mt], 0, 0, 0);
            }
        }
        const int n = l & 15, r0w = (l >> 4) * 4;
        #pragma unroll
        for (int mt = 0; mt < 4; ++mt)
            #pragma unroll
            for (int r = 0; r < 4; ++r)
                pt[mt * 16 + r0w + r][n] = acc[mt][r];
    };

    // ---- prologue: chunk 0's static dot ----
    f32x2 P2[CH], corr[CH];
    mfma_to_pt(0);
    {
        f32x4 pa = *(const f32x4*)&pt[u][0];
        f32x4 pb = *(const f32x4*)&pt[u][4];
        f32x4 pc = *(const f32x4*)&pt[u][8];
        f32x4 pd = *(const f32x4*)&pt[u][12];
        #pragma unroll
        for (int ci = 0; ci < 4; ++ci) {
            P2[ci]     = f32x2{pa[ci], pc[ci]} + bb;
            P2[ci + 4] = f32x2{pb[ci], pd[ci]} + bb;
        }
    }
    #pragma unroll
    for (int j = 0; j < CH; ++j) corr[j] = f32x2{0.f, 0.f};

    #pragma unroll 1
    for (int c = 0; c < NCH; ++c) {
        const int i0 = c * CH;

        // ---- pack chunk c-1's preds into ypk (needed by next MFMA) ----
        if (c > 0 && l < 16) {
            const int ss = l >> 3, j = l & 7;
            const int row = i0 + 56 + j;
            f32x2 v = yw[ss][row];
            unsigned short hA = f2bf(v.x);
            unsigned short hB = f2bf(v.y);
            ypk[ss][0][row] = (unsigned int)hA | ((unsigned int)f2bf(v.x - bf2f(hA)) << 16);
            ypk[ss][1][row] = (unsigned int)hB | ((unsigned int)f2bf(v.y - bf2f(hB)) << 16);
        }

        // ---- EARLY: MFMA + transpose for chunk c+1 (rows i0+64..71 are 0) ----
        if (c + 1 < NCH) mfma_to_pt(i0 + CH);

        // ---- prefetch E + predprev ----
        f32x2 ev8[CH];
        #pragma unroll
        for (int q = 0; q < 4; ++q) {
            f32x4 e4 = *(const f32x4*)&EV[i0 + 2 * q];
            ev8[2 * q]     = f32x2{e4[0], e4[1]};
            ev8[2 * q + 1] = f32x2{e4[2], e4[3]};
        }
        f32x2 predprev = Y[i0 + 63];

        // ---- 8 sequential steps ----
        #pragma unroll
        for (int ci = 0; ci < CH; ++ci) {
            const int i = i0 + ci;
            const f32x2 y1a = Y[i + 2 * h];
            const f32x2 y1b = Y[i + 2 * h + 1];

            f32x2 sg;
            sg.x = sigmoidf(P2[ci].x);
            sg.y = sigmoidf(P2[ci].y);

            f32x2 va = w3own * sg + wo1a * y1a + wo1b * y1b;
            f32x2 vb = w3oth * sg + wo2a * y1a + wo2b * y1b;

            f32x2 cc = va + xchg16(vb, s);
            cc.x = dpp_add<0xB1>(cc.x);  cc.y = dpp_add<0xB1>(cc.y);
            cc.x = dpp_add<0x4E>(cc.x);  cc.y = dpp_add<0x4E>(cc.y);
            cc.x = dpp_add<0x141>(cc.x); cc.y = dpp_add<0x141>(cc.y);
            cc.x = dpp_add<0x128>(cc.x); cc.y = dpp_add<0x128>(cc.y);
            cc = fold32(cc, s32);

            const f32x2 pred = cc + ev8[ci] + predprev;

            // within-chunk tails: tap 64-d (d = cj-ci) -> w2x[15-d]
            #pragma unroll
            for (int cj = ci + 1; cj < CH; ++cj)
                P2[cj] += w2x[15 - (cj - ci)] * pred;
            // next-chunk corrections: tap 56+ci-cin -> w2x[7+ci-cin]
            #pragma unroll
            for (int cin = 0; cin < CH; ++cin)
                corr[cin] += w2x[7 + ci - cin] * pred;

            if ((l & 47) == 0) Y[i + NIN] = pred;
            predprev = pred;
        }

        // ---- assemble next chunk's P2 from pt + corrections ----
        if (c + 1 < NCH) {
            f32x4 pa = *(const f32x4*)&pt[u][0];
            f32x4 pb = *(const f32x4*)&pt[u][4];
            f32x4 pc = *(const f32x4*)&pt[u][8];
            f32x4 pd = *(const f32x4*)&pt[u][12];
            #pragma unroll
            for (int ci = 0; ci < 4; ++ci) {
                P2[ci]     = f32x2{pa[ci], pc[ci]} + bb + corr[ci];
                P2[ci + 4] = f32x2{pb[ci], pd[ci]} + bb + corr[ci + 4];
            }
            #pragma unroll
            for (int j = 0; j < CH; ++j) corr[j] = f32x2{0.f, 0.f};
        }
    }

    // ---- dump ----
    {
        f32x2 a0 = yw[0][NIN + 2 * l];
        f32x2 a1 = yw[1][NIN + 2 * l];
        f32x2 c0 = yw[0][NIN + 2 * l + 1];
        f32x2 c1 = yw[1][NIN + 2 * l + 1];
        *(float4*)&out[bA * (NOUT * NTGT) + l * 4] = make_float4(a0.x, a1.x, c0.x, c1.x);
        *(float4*)&out[bB * (NOUT * NTGT) + l * 4] = make_float4(a0.y, a1.y, c0.y, c1.y);
    }
}

extern "C" void kernel_launch(void* const* d_in, const int* in_sizes, int n_in,
                              void* d_out, int out_size, void* d_ws, size_t ws_size,
                              hipStream_t stream) {
    (void)in_sizes; (void)n_in; (void)out_size; (void)ws_size;
    const float* target = (const float*)d_in[0];
    const float* exog   = (const float*)d_in[1];
    const float* W1     = (const float*)d_in[2];
    const float* b1     = (const float*)d_in[3];
    const float* W2     = (const float*)d_in[4];
    const float* b2     = (const float*)d_in[5];
    const float* W3     = (const float*)d_in[6];
    const float* b3     = (const float*)d_in[7];
    float* out = (float*)d_out;
    unsigned char* ws = (unsigned char*)d_ws;

    hipLaunchKernelGGL(narx_prepack_kernel, dim3(1), dim3(256), 0, stream,
                       W1, W2, W3, b2, ws);
    hipLaunchKernelGGL(narx_exog_kernel, dim3(NB), dim3(256), 0, stream,
                       exog, b1, b3, ws, out);
    hipLaunchKernelGGL(narx_recur_kernel, dim3(NB / 2), dim3(64), 0, stream,
                       target, W1, W2, b2, W3, ws, out);
}

// Round 18
// 197.479 us; speedup vs baseline: 1.3010x; 1.0296x over previous
//
#include <hip/hip_runtime.h>
#include <math.h>

#define NB 8192
#define NIN 64
#define NOUT 128
#define NHID 32
#define NEXO 3
#define EXROWS 192
#define NTGT 2

typedef float f32x2 __attribute__((ext_vector_type(2)));
typedef float f32x4 __attribute__((ext_vector_type(4)));
typedef int   i32x4 __attribute__((ext_vector_type(4)));
typedef short bf16x8 __attribute__((ext_vector_type(8)));

// ws layout (bytes): [0) W2A bf16[6144] | [12288) W2BH bf16[4096] |
// [20480) W2BL bf16[4096] | [28672) WP float[672] (w1e2 384 | w3l 192 | b2l 96)
#define WS_W2A  0
#define WS_W2BH 12288
#define WS_W2BL 20480
#define WS_WP   28672

__device__ __forceinline__ float sigmoidf(float x) {
    return 1.0f / (1.0f + __expf(-x));
}

__device__ __forceinline__ unsigned short f2bf(float x) {   // RNE float->bf16
    unsigned int u = __float_as_uint(x);
    unsigned int r = u + 0x7fffu + ((u >> 16) & 1u);
    return (unsigned short)(r >> 16);
}
__device__ __forceinline__ float bf2f(unsigned short h) {
    return __uint_as_float((unsigned int)h << 16);
}

template<int CTRL>
__device__ __forceinline__ float dpp_add(float x) {
    int p = __builtin_amdgcn_update_dpp(0, __float_as_int(x), CTRL, 0xf, 0xf, true);
    return x + __int_as_float(p);
}

#if __has_builtin(__builtin_amdgcn_permlane16_swap)
__device__ __forceinline__ float xchg16(float v, int s) {
    auto rx = __builtin_amdgcn_permlane16_swap(__float_as_uint(v), __float_as_uint(v), false, false);
    return s ? __uint_as_float(rx[0]) : __uint_as_float(rx[1]);
}
#else
__device__ __forceinline__ float xchg16(float v, int s) {
    (void)s;
    return __int_as_float(__builtin_amdgcn_ds_swizzle(__float_as_int(v), 0x401f));
}
#endif

__device__ __forceinline__ float fold32(float v, int s32) {
    auto rx = __builtin_amdgcn_permlane32_swap(__float_as_uint(v), __float_as_uint(v), false, false);
    return v + (s32 ? __uint_as_float(rx[0]) : __uint_as_float(rx[1]));
}

// -------------------------------------------------------------------------
// Kernel A0: one-block weight prepack into ws (unchanged from round 16).
// -------------------------------------------------------------------------
__global__ __launch_bounds__(256) void narx_prepack_kernel(
    const float* __restrict__ W1, const float* __restrict__ W2,
    const float* __restrict__ W3, const float* __restrict__ b2,
    unsigned char* __restrict__ ws)
{
    const int tid = threadIdx.x;
    unsigned short* w2a  = (unsigned short*)(ws + WS_W2A);
    unsigned short* w2bh = (unsigned short*)(ws + WS_W2BH);
    unsigned short* w2bl = (unsigned short*)(ws + WS_W2BL);
    float* wp = (float*)(ws + WS_WP);

    for (int idx = tid; idx < 6144; idx += 256) {
        int rem = idx;
        int j = rem & 7;  rem >>= 3;
        int lg = rem & 3; rem >>= 2;
        int col = rem & 15; rem >>= 4;
        int kt = rem & 1; rem >>= 1;
        int mt = rem & 1; rem >>= 1;
        int e = rem;
        int row = 64 + e * 32 + mt * 16 + col;
        int t = kt * 32 + lg * 8 + j;
        w2a[idx] = f2bf(W2[(size_t)row * NIN + t]);
    }
    for (int idx = tid; idx < 4096; idx += 256) {
        int rem = idx;
        int j = rem & 7;   rem >>= 3;
        int k0g = rem & 3; rem >>= 2;
        int m0 = rem & 15; rem >>= 4;
        int kt = rem & 1;  rem >>= 1;
        int mt = rem;
        int row = mt * 16 + m0;
        int t = kt * 32 + k0g * 8 + j;
        float x = W2[(size_t)row * NIN + t];
        unsigned short hi = f2bf(x);
        w2bh[idx] = hi;
        w2bl[idx] = f2bf(x - bf2f(hi));
    }
    for (int idx = tid; idx < 384; idx += 256) {
        int e = idx >> 7;
        int r = idx & 127;
        int t = r >> 1, o = r & 1;
        wp[idx] = W1[o * 320 + t * 5 + 2 + e];
    }
    if (tid < 192) wp[384 + tid] = W3[(tid / 96) * 160 + 64 + (tid % 96)];
    if (tid < 96)  wp[576 + tid] = b2[64 + tid];
}

// -------------------------------------------------------------------------
// Kernel A v2 (MFMA): unchanged from round 16.
// -------------------------------------------------------------------------
__global__ __launch_bounds__(256, 4) void narx_exog_kernel(
    const float* __restrict__ exog,
    const float* __restrict__ b1, const float* __restrict__ b3,
    const unsigned char* __restrict__ ws,
    float* __restrict__ E)
{
    __shared__ __align__(16) float exs[NEXO][EXROWS];
    __shared__ __align__(16) unsigned short exrep[NEXO * 8][200];
    __shared__ __align__(16) float2 w1e2[NEXO][NIN];
    __shared__ __align__(16) float w3l[2][96];
    __shared__ __align__(16) float b2l[96];

    const unsigned short* w2a = (const unsigned short*)(ws + WS_W2A);
    const float* wp = (const float*)(ws + WS_WP);

    const int tid = threadIdx.x;
    const int b = blockIdx.x;
    const float* exb = exog + (size_t)b * (EXROWS * NEXO);

    for (int idx = tid; idx < EXROWS * NEXO; idx += 256) {
        int t = idx / 3;
        int e = idx - t * 3;
        exs[e][t] = exb[idx];
    }
    for (int idx = tid; idx < 384; idx += 256) ((float*)w1e2)[idx] = wp[idx];
    if (tid < 192) ((float*)w3l)[tid] = wp[384 + tid];
    if (tid < 96)  b2l[tid] = wp[576 + tid];
    __syncthreads();

    for (int idx = tid; idx < NEXO * 8 * 192; idx += 256) {
        int e = idx / 1536;
        int rem = idx - e * 1536;
        int r = rem / 192;
        int q = rem - r * 192;
        float v = (q + r < 192) ? exs[e][q + r] : 0.f;
        exrep[e * 8 + r][q] = f2bf(v);
    }
    __syncthreads();

    const int wv = tid >> 6;
    const int l  = tid & 63;
    const int iw = wv * 32;
    const int lg = l >> 4;
    const int col = l & 15;

    float acc0[2] = {0.f, 0.f};
    float acc1[2] = {0.f, 0.f};

    #pragma unroll 1
    for (int e = 0; e < NEXO; ++e) {
        f32x4 b2v[2], w30v[2], w31v[2];
        #pragma unroll
        for (int mt = 0; mt < 2; ++mt) {
            b2v[mt]  = *(const f32x4*)&b2l[e * 32 + mt * 16 + lg * 4];
            w30v[mt] = *(const f32x4*)&w3l[0][e * 32 + mt * 16 + lg * 4];
            w31v[mt] = *(const f32x4*)&w3l[1][e * 32 + mt * 16 + lg * 4];
        }

        f32x4 cacc[2][2];
        #pragma unroll
        for (int mt = 0; mt < 2; ++mt)
            #pragma unroll
            for (int nt = 0; nt < 2; ++nt)
                cacc[mt][nt] = b2v[mt];

        #pragma unroll
        for (int kt = 0; kt < 2; ++kt) {
            bf16x8 af[2], bfr[2];
            #pragma unroll
            for (int mt = 0; mt < 2; ++mt)
                af[mt] = *(const bf16x8*)(w2a + ((size_t)((e * 2 + mt) * 2 + kt)) * 512
                                              + col * 32 + lg * 8);
            #pragma unroll
            for (int nt = 0; nt < 2; ++nt)
                bfr[nt] = *(const bf16x8*)&exrep[e * 8 + (l & 7)]
                              [iw + nt * 16 + kt * 32 + lg * 8 + ((l >> 3) & 1) * 8];
            #pragma unroll
            for (int mt = 0; mt < 2; ++mt)
                #pragma unroll
                for (int nt = 0; nt < 2; ++nt)
                    cacc[mt][nt] = __builtin_amdgcn_mfma_f32_16x16x32_bf16(
                        af[mt], bfr[nt], cacc[mt][nt], 0, 0, 0);
        }

        #pragma unroll
        for (int mt = 0; mt < 2; ++mt)
            #pragma unroll
            for (int nt = 0; nt < 2; ++nt) {
                #pragma unroll
                for (int r = 0; r < 4; ++r) {
                    float sg = sigmoidf(cacc[mt][nt][r]);
                    acc0[nt] += w30v[mt][r] * sg;
                    acc1[nt] += w31v[mt][r] * sg;
                }
            }

        const float* exs_e = &exs[e][0];
        #pragma unroll
        for (int dt = 0; dt < 16; ++dt) {
            float2 wv2 = w1e2[e][lg * 16 + dt];
            float x0 = exs_e[iw + l + dt];
            float x1 = exs_e[iw + 16 + l + dt];
            acc0[0] += wv2.x * x0;
            acc1[0] += wv2.y * x0;
            acc0[1] += wv2.x * x1;
            acc1[1] += wv2.y * x1;
        }
    }

    #pragma unroll
    for (int nt = 0; nt < 2; ++nt) {
        acc0[nt] += __shfl_xor(acc0[nt], 16, 64);
        acc0[nt] += __shfl_xor(acc0[nt], 32, 64);
        acc1[nt] += __shfl_xor(acc1[nt], 16, 64);
        acc1[nt] += __shfl_xor(acc1[nt], 32, 64);
    }
    if (lg == 0) {
        const float bias0 = b1[0] + b3[0];
        const float bias1 = b1[1] + b3[1];
        #pragma unroll
        for (int nt = 0; nt < 2; ++nt) {
            int i = iw + nt * 16 + col;
            *(float2*)&E[(size_t)b * (NOUT * NTGT) + i * 2] =
                make_float2(acc0[nt] + bias0, acc1[nt] + bias1);
        }
    }
}

// -------------------------------------------------------------------------
// Kernel B v18: ONE batch per 64-thread wave (8192 blocks = 8 waves/SIMD
// supply), scalar math, 16-step chunks (MFMA N=16 cols = 16 lags, 8 chunks).
// A-fragments reloaded from L1/L2 each chunk (opaque offset prevents
// hoisting) to keep VGPR low for occupancy. No corr pipelining — TLP hides
// the MFMA phase across waves. No barriers at all (single wave).
// -------------------------------------------------------------------------
#define CH 16
#define NCH 8

__global__ __launch_bounds__(64) void narx_recur_kernel(
    const float* __restrict__ target,
    const float* __restrict__ W1,
    const float* __restrict__ W2, const float* __restrict__ b2,
    const float* __restrict__ W3,
    const unsigned char* __restrict__ ws,
    float* __restrict__ out)
{
    __shared__ __align__(16) float yw[NTGT][192];          // fp32 window, 1.5 KB
    __shared__ __align__(16) unsigned int ypk[NTGT][200];  // {hi|lo<<16} bf16 pair, 1.6 KB
    __shared__ __align__(16) float ew[NTGT][NOUT];         // E, 1 KB
    __shared__ __align__(16) float pt[64][17];             // transpose buf, 4.25 KB

    const unsigned short* w2bh = (const unsigned short*)(ws + WS_W2BH);
    const unsigned short* w2bl = (const unsigned short*)(ws + WS_W2BL);

    const int l = threadIdx.x;
    const int s   = (l >> 4) & 1;                 // series group
    const int h   = (l & 15) | ((l >> 5) << 4);   // hidden unit within series
    const int u   = s * NHID + h;                 // global unit
    const int s32 = (l >> 5) & 1;
    const size_t b = blockIdx.x;

    for (int i = l; i < NTGT * 200; i += 64) ((unsigned int*)ypk)[i] = 0u;

    {   // E -> LDS (lane covers rows 2l, 2l+1)
        float4 e4 = *(const float4*)&out[b * (NOUT * NTGT) + l * 4];
        ew[0][2 * l]     = e4.x;
        ew[1][2 * l]     = e4.y;
        ew[0][2 * l + 1] = e4.z;
        ew[1][2 * l + 1] = e4.w;
    }
    {   // initial window row l: fp32 + packed bf16 hi/lo
        float2 tv = *(const float2*)&target[b * (NIN * NTGT) + l * 2];
        yw[0][l] = tv.x;
        yw[1][l] = tv.y;
        float v[2] = {tv.x, tv.y};
        #pragma unroll
        for (int ss = 0; ss < 2; ++ss) {
            unsigned short hi = f2bf(v[ss]);
            unsigned short lo = f2bf(v[ss] - bf2f(hi));
            ypk[ss][l] = (unsigned int)hi | ((unsigned int)lo << 16);
        }
    }

    // ---- per-lane constants ----
    const float bb    = b2[u];
    const float w3own = W3[s * 160 + u];
    const float w3oth = W3[(1 - s) * 160 + u];
    const float wo1a  = W1[s * 320 + (2 * h) * 5 + s];
    const float wo1b  = W1[s * 320 + (2 * h + 1) * 5 + s];
    const float wo2a  = W1[(1 - s) * 320 + (2 * h) * 5 + s];
    const float wo2b  = W1[(1 - s) * 320 + (2 * h + 1) * 5 + s];
    float w2x[15];                               // own-unit taps 49..63
    #pragma unroll
    for (int j = 0; j < 15; ++j) w2x[j] = W2[(size_t)u * NIN + 49 + j];

    float* Y = &yw[s][0];
    const float* EV = &ew[s][0];

    // B-frag addressing: col n = l&15 = lag; k = (l>>4)*8 + j (+ kt*32)
    const int lag = l & 15;
    const int bk0 = (l >> 4) * 8;
    // A-frag lane mapping
    const int m0 = l & 15, k0g = l >> 4;

    int zoff = 0;   // opaque zero: forces per-chunk A-frag reload (keeps VGPR low)

    #pragma unroll 1
    for (int c = 0; c < NCH; ++c) {
        const int i0 = c * CH;
        asm volatile("" : "+v"(zoff));

        // ---- pack prev chunk's 16 preds (rows i0+48..63) into ypk ----
        if (c > 0 && l < 32) {
            const int ss = l >> 4, j = l & 15;
            const int row = i0 + 48 + j;
            float v = yw[ss][row];
            unsigned short hi = f2bf(v);
            ypk[ss][row] = (unsigned int)hi | ((unsigned int)f2bf(v - bf2f(hi)) << 16);
        }

        // ---- MFMA static dot: P[u][lag] over known rows (future rows 0) ----
        f32x4 acc[4];
        #pragma unroll
        for (int mt = 0; mt < 4; ++mt) acc[mt] = f32x4{0.f, 0.f, 0.f, 0.f};

        #pragma unroll
        for (int kt = 0; kt < 2; ++kt) {
            const int base = i0 + lag + bk0 + kt * 32;
            unsigned int r0[8], r1[8];
            #pragma unroll
            for (int j = 0; j < 8; ++j) { r0[j] = ypk[0][base + j]; r1[j] = ypk[1][base + j]; }
            i32x4 h0v, l0v, h1v, l1v;
            #pragma unroll
            for (int j2 = 0; j2 < 4; ++j2) {
                h0v[j2] = (int)__builtin_amdgcn_perm(r0[2*j2+1], r0[2*j2], 0x05040100u);
                l0v[j2] = (int)__builtin_amdgcn_perm(r0[2*j2+1], r0[2*j2], 0x07060302u);
                h1v[j2] = (int)__builtin_amdgcn_perm(r1[2*j2+1], r1[2*j2], 0x05040100u);
                l1v[j2] = (int)__builtin_amdgcn_perm(r1[2*j2+1], r1[2*j2], 0x07060302u);
            }
            const bf16x8 bh0 = __builtin_bit_cast(bf16x8, h0v);
            const bf16x8 bl0 = __builtin_bit_cast(bf16x8, l0v);
            const bf16x8 bh1 = __builtin_bit_cast(bf16x8, h1v);
            const bf16x8 bl1 = __builtin_bit_cast(bf16x8, l1v);
            #pragma unroll
            for (int mt = 0; mt < 4; ++mt) {
                const int off = ((mt * 2 + kt) * 16 + m0) * 32 + k0g * 8 + zoff;
                const bf16x8 ah = *(const bf16x8*)(w2bh + off);
                const bf16x8 al = *(const bf16x8*)(w2bl + off);
                const bf16x8 bh = (mt < 2) ? bh0 : bh1;
                const bf16x8 bl = (mt < 2) ? bl0 : bl1;
                acc[mt] = __builtin_amdgcn_mfma_f32_16x16x32_bf16(ah, bh, acc[mt], 0, 0, 0);
                acc[mt] = __builtin_amdgcn_mfma_f32_16x16x32_bf16(ah, bl, acc[mt], 0, 0, 0);
                acc[mt] = __builtin_amdgcn_mfma_f32_16x16x32_bf16(al, bh, acc[mt], 0, 0, 0);
            }
        }

        // ---- transpose C via pt[unit][lag] ----
        {
            const int n = l & 15, r0w = (l >> 4) * 4;
            #pragma unroll
            for (int mt = 0; mt < 4; ++mt)
                #pragma unroll
                for (int r = 0; r < 4; ++r)
                    pt[mt * 16 + r0w + r][n] = acc[mt][r];
        }
        float P2[CH];
        {
            f32x4 pa = *(const f32x4*)&pt[u][0];
            f32x4 pb = *(const f32x4*)&pt[u][4];
            f32x4 pc = *(const f32x4*)&pt[u][8];
            f32x4 pd = *(const f32x4*)&pt[u][12];
            #pragma unroll
            for (int j = 0; j < 4; ++j) {
                P2[j]      = pa[j] + bb;
                P2[j + 4]  = pb[j] + bb;
                P2[j + 8]  = pc[j] + bb;
                P2[j + 12] = pd[j] + bb;
            }
        }

        // ---- prefetch E + predprev ----
        float ev16[CH];
        #pragma unroll
        for (int q = 0; q < 4; ++q) {
            f32x4 e4 = *(const f32x4*)&EV[i0 + 4 * q];
            ev16[4*q+0] = e4[0]; ev16[4*q+1] = e4[1];
            ev16[4*q+2] = e4[2]; ev16[4*q+3] = e4[3];
        }
        float predprev = Y[i0 + 63];

        // ---- 16 sequential steps ----
        #pragma unroll
        for (int ci = 0; ci < CH; ++ci) {
            const int i = i0 + ci;
            const float y1a = Y[i + 2 * h];
            const float y1b = Y[i + 2 * h + 1];

            const float sg = sigmoidf(P2[ci]);
            float va = w3own * sg + wo1a * y1a + wo1b * y1b;
            float vb = w3oth * sg + wo2a * y1a + wo2b * y1b;

            float cc = va + xchg16(vb, s);
            cc = dpp_add<0xB1>(cc);    // xor1
            cc = dpp_add<0x4E>(cc);    // xor2
            cc = dpp_add<0x141>(cc);   // xor7
            cc = dpp_add<0x128>(cc);   // xor8
            cc = fold32(cc, s32);

            const float pred = cc + ev16[ci] + predprev;

            // in-chunk recurrent tails: tap 64-d -> w2x[15-d]
            #pragma unroll
            for (int cj = ci + 1; cj < CH; ++cj)
                P2[cj] += w2x[15 - (cj - ci)] * pred;

            if ((l & 47) == 0) Y[i + NIN] = pred;   // lane 0 (s=0), 16 (s=1)
            predprev = pred;
        }
    }

    // ---- dump: lane l covers output rows 2l, 2l+1 ----
    {
        float4 ov;
        ov.x = yw[0][NIN + 2 * l];
        ov.y = yw[1][NIN + 2 * l];
        ov.z = yw[0][NIN + 2 * l + 1];
        ov.w = yw[1][NIN + 2 * l + 1];
        *(float4*)&out[b * (NOUT * NTGT) + l * 4] = ov;
    }
}

extern "C" void kernel_launch(void* const* d_in, const int* in_sizes, int n_in,
                              void* d_out, int out_size, void* d_ws, size_t ws_size,
                              hipStream_t stream) {
    (void)in_sizes; (void)n_in; (void)out_size; (void)ws_size;
    const float* target = (const float*)d_in[0];
    const float* exog   = (const float*)d_in[1];
    const float* W1     = (const float*)d_in[2];
    const float* b1     = (const float*)d_in[3];
    const float* W2     = (const float*)d_in[4];
    const float* b2     = (const float*)d_in[5];
    const float* W3     = (const float*)d_in[6];
    const float* b3     = (const float*)d_in[7];
    float* out = (float*)d_out;
    unsigned char* ws = (unsigned char*)d_ws;

    hipLaunchKernelGGL(narx_prepack_kernel, dim3(1), dim3(256), 0, stream,
                       W1, W2, W3, b2, ws);
    hipLaunchKernelGGL(narx_exog_kernel, dim3(NB), dim3(256), 0, stream,
                       exog, b1, b3, ws, out);
    hipLaunchKernelGGL(narx_recur_kernel, dim3(NB), dim3(64), 0, stream,
                       target, W1, W2, b2, W3, ws, out);
}